// Round 1
// baseline (1309.817 us; speedup 1.0000x reference)
//
#include <hip/hip_runtime.h>

namespace {
constexpr int kNH = 8;
constexpr int kK  = 1024;
constexpr int kD  = 128;
constexpr int kB  = 32768;

constexpr int BM  = 64;    // z rows per block
constexpr int KT  = 64;    // codes per k-tile
constexpr int PAD = 68;    // LDS row stride in floats (16B-aligned, conflict-light)
constexpr float kMargin = 0.0625f;  // >> 2x fp32 coarse error bound (~1e-4)
}

// ---------------------------------------------------------------------------
// Pass A: tiled fp32 coarse pass. Per block: one head, 64 z-rows, all 1024 codes.
// score[k] = c_sq[k] - 2 * dot(z, c_k)   (z_sq constant per row -> irrelevant)
// Tracks top-2 per row; rows whose (2nd - 1st) <= margin go to a worklist.
// ---------------------------------------------------------------------------
__global__ __launch_bounds__(256, 2)
void pq_coarse(const float* __restrict__ z, const float* __restrict__ cb,
               float* __restrict__ out_zq, float* __restrict__ out_idx,
               unsigned int* wl_count, unsigned int* wl, unsigned int wl_cap)
{
    __shared__ float zT[kD][PAD];   // zT[d][row]
    __shared__ float cT[kD][PAD];   // cT[d][code]
    __shared__ float csq_s[KT];
    __shared__ int   bidx_s[BM];

    const int t  = threadIdx.x;
    const int h  = blockIdx.y;
    const int b0 = blockIdx.x * BM;
    const int tx = t & 15;          // code-group (4 codes)
    const int ty = t >> 4;          // row-group (4 rows)
    const int r8 = t & 7;           // staging: row within 8-row slab
    const int d4 = t >> 3;          // staging: float4 column 0..31

    // ---- stage z tile transposed ----
    {
        const float* zp = z + (size_t)(b0 + r8) * (kNH * kD) + h * kD + 4 * d4;
        #pragma unroll
        for (int it = 0; it < BM / 8; ++it) {
            float4 v = *(const float4*)(zp + (size_t)(8 * it) * (kNH * kD));
            int r = r8 + 8 * it;
            zT[4 * d4 + 0][r] = v.x;
            zT[4 * d4 + 1][r] = v.y;
            zT[4 * d4 + 2][r] = v.z;
            zT[4 * d4 + 3][r] = v.w;
        }
    }

    float best1[4], best2[4];
    int   ibest[4];
    #pragma unroll
    for (int i = 0; i < 4; ++i) { best1[i] = 3.4e38f; best2[i] = 3.4e38f; ibest[i] = 0; }

    for (int kt = 0; kt < kK / KT; ++kt) {
        __syncthreads();   // z staged (iter 0) / previous tile's reads done
        // ---- stage c tile transposed ----
        {
            const float* cp = cb + ((size_t)h * kK + kt * KT + r8) * kD + 4 * d4;
            #pragma unroll
            for (int it = 0; it < KT / 8; ++it) {
                float4 v = *(const float4*)(cp + (size_t)(8 * it) * kD);
                int r = r8 + 8 * it;
                cT[4 * d4 + 0][r] = v.x;
                cT[4 * d4 + 1][r] = v.y;
                cT[4 * d4 + 2][r] = v.z;
                cT[4 * d4 + 3][r] = v.w;
            }
        }
        if (t < KT) csq_s[t] = 0.0f;
        __syncthreads();
        // ---- cooperative c_sq for this tile (4 partials per code) ----
        {
            int kk = t & 63, part = t >> 6;
            float s = 0.f;
            #pragma unroll
            for (int i = 0; i < 32; ++i) {
                float v = cT[32 * part + i][kk];
                s = fmaf(v, v, s);
            }
            atomicAdd(&csq_s[kk], s);
        }
        __syncthreads();
        // ---- 4x4 register outer product over d, 2 interleaved accumulators ----
        float accA[4][4] = {{0}}, accB[4][4] = {{0}};
        #pragma unroll 2
        for (int d = 0; d < kD; d += 2) {
            float4 za = *(const float4*)&zT[d][4 * ty];
            float4 ca = *(const float4*)&cT[d][4 * tx];
            float4 zb = *(const float4*)&zT[d + 1][4 * ty];
            float4 cv = *(const float4*)&cT[d + 1][4 * tx];
            float zav[4] = {za.x, za.y, za.z, za.w};
            float cav[4] = {ca.x, ca.y, ca.z, ca.w};
            float zbv[4] = {zb.x, zb.y, zb.z, zb.w};
            float cbv[4] = {cv.x, cv.y, cv.z, cv.w};
            #pragma unroll
            for (int i = 0; i < 4; ++i) {
                #pragma unroll
                for (int j = 0; j < 4; ++j) {
                    accA[i][j] = fmaf(zav[i], cav[j], accA[i][j]);
                    accB[i][j] = fmaf(zbv[i], cbv[j], accB[i][j]);
                }
            }
        }
        // ---- scores + running top-2 (ascending k per thread -> first-min ties) ----
        #pragma unroll
        for (int j = 0; j < 4; ++j) {
            int kk = 4 * tx + j;
            float cs = csq_s[kk];
            int kg = kt * KT + kk;
            #pragma unroll
            for (int i = 0; i < 4; ++i) {
                float s = fmaf(-2.0f, accA[i][j] + accB[i][j], cs);
                if (s < best1[i]) { best2[i] = best1[i]; best1[i] = s; ibest[i] = kg; }
                else if (s < best2[i]) { best2[i] = s; }
            }
        }
    }
    __syncthreads();
    // ---- cross-thread reduction (16 partials per row), scratch aliased on zT ----
    float* redv1 = &zT[0][0];                  // BM*16 floats
    float* redv2 = redv1 + BM * 16;            // BM*16 floats
    int*   redi  = (int*)(redv2 + BM * 16);    // BM*16 ints
    #pragma unroll
    for (int i = 0; i < 4; ++i) {
        int r = 4 * ty + i;
        redv1[r * 16 + tx] = best1[i];
        redv2[r * 16 + tx] = best2[i];
        redi [r * 16 + tx] = ibest[i];
    }
    __syncthreads();
    if (t < BM) {
        int r = t;
        float b1 = redv1[r * 16 + 0], b2 = redv2[r * 16 + 0];
        int i1 = redi[r * 16 + 0];
        #pragma unroll
        for (int x = 1; x < 16; ++x) {
            float vb1 = redv1[r * 16 + x], vb2 = redv2[r * 16 + x];
            int vi1 = redi[r * 16 + x];
            if (vb1 < b1 || (vb1 == b1 && vi1 < i1)) {
                b2 = fminf(b1, vb2); b1 = vb1; i1 = vi1;
            } else {
                b2 = fminf(b2, vb1);
            }
        }
        bidx_s[r] = i1;
        int gid = (b0 + r) * kNH + h;
        out_idx[gid] = (float)i1;
        if (wl_cap > 0u && (b2 - b1) <= kMargin) {
            unsigned int pos = atomicAdd(wl_count, 1u);
            if (pos < wl_cap) wl[pos] = (unsigned int)gid;
        }
    }
    __syncthreads();
    // ---- gather zq rows (exact copies of codebook rows) ----
    {
        int r = t >> 2, q = t & 3;
        const float* src = cb + ((size_t)h * kK + bidx_s[r]) * kD;
        float* dst = out_zq + (size_t)(b0 + r) * (kNH * kD) + h * kD;
        #pragma unroll
        for (int m = 0; m < 8; ++m) {
            int jj = 4 * m + q;
            *(float4*)(dst + 4 * jj) = *(const float4*)(src + 4 * jj);
        }
    }
}

// ---------------------------------------------------------------------------
// Pass B: exact fp64 argmin over all 1024 codes for flagged (b,h) pairs.
// One block per worklist entry (grid-strided, static grid for graph capture).
// ---------------------------------------------------------------------------
__global__ __launch_bounds__(256)
void pq_exact(const float* __restrict__ z, const float* __restrict__ cb,
              float* __restrict__ out_zq, float* __restrict__ out_idx,
              const unsigned int* wl_count, const unsigned int* wl,
              unsigned int wl_cap)
{
    if (wl_cap == 0u) return;
    __shared__ float  zs[kD];
    __shared__ double rv[256];
    __shared__ int    ri[256];
    unsigned int n = *wl_count;
    if (n > wl_cap) n = wl_cap;
    const int t = threadIdx.x;
    for (unsigned int e = blockIdx.x; e < n; e += gridDim.x) {
        unsigned int id = wl[e];
        int b = (int)(id / kNH), h = (int)(id % kNH);
        if (t < kD) zs[t] = z[(size_t)b * (kNH * kD) + h * kD + t];
        __syncthreads();
        double bv = 1e300; int bi = 0;
        #pragma unroll
        for (int kk = 0; kk < 4; ++kk) {
            int k = t * 4 + kk;
            const float* c = cb + ((size_t)h * kK + k) * kD;
            double s = 0.0;
            for (int d = 0; d < kD; ++d) {
                double diff = (double)zs[d] - (double)c[d];
                s = fma(diff, diff, s);
            }
            if (s < bv) { bv = s; bi = k; }
        }
        rv[t] = bv; ri[t] = bi;
        __syncthreads();
        for (int s2 = 128; s2 > 0; s2 >>= 1) {
            if (t < s2) {
                if (rv[t + s2] < rv[t] || (rv[t + s2] == rv[t] && ri[t + s2] < ri[t])) {
                    rv[t] = rv[t + s2]; ri[t] = ri[t + s2];
                }
            }
            __syncthreads();
        }
        int kbest = ri[0];
        if (t == 0) out_idx[id] = (float)kbest;
        if (t < kD)
            out_zq[(size_t)b * (kNH * kD) + h * kD + t] =
                cb[((size_t)h * kK + kbest) * kD + t];
        __syncthreads();
    }
}

extern "C" void kernel_launch(void* const* d_in, const int* in_sizes, int n_in,
                              void* d_out, int out_size, void* d_ws, size_t ws_size,
                              hipStream_t stream)
{
    const float* z  = (const float*)d_in[0];
    const float* cb = (const float*)d_in[1];
    float* out_zq  = (float*)d_out;
    float* out_idx = out_zq + (size_t)kB * kNH * kD;

    unsigned int* wl_count = (unsigned int*)d_ws;
    unsigned int* wl = wl_count + 1;
    unsigned int cap = 0;
    if (ws_size >= 64) {
        size_t c = ws_size / 4 - 1;
        cap = (unsigned int)(c > 262144 ? 262144 : c);
        hipMemsetAsync(d_ws, 0, 4, stream);   // zero worklist counter each launch
    }

    dim3 grid(kB / BM, kNH);
    pq_coarse<<<grid, 256, 0, stream>>>(z, cb, out_zq, out_idx, wl_count, wl, cap);
    pq_exact<<<256, 256, 0, stream>>>(z, cb, out_zq, out_idx, wl_count, wl, cap);
}

// Round 2
// 426.805 us; speedup vs baseline: 3.0689x; 3.0689x over previous
//
#include <hip/hip_runtime.h>

namespace {
constexpr int kNH = 8;
constexpr int kK  = 1024;
constexpr int kD  = 128;
constexpr int kB  = 32768;

constexpr int BM  = 64;    // z rows per block (MFMA path)
constexpr float kMarginMfma = 0.02f;
constexpr float kMarginF32  = 0.0625f;

// d_ws layout (MFMA path): [0]=wl_count u32; csq @1024 (32KB);
// cb_hi @64KB (2MB); cb_lo @64KB+2MB (2MB); worklist @64KB+4MB.
constexpr size_t kOffCsq = 1024;
constexpr size_t kOffCbH = 65536;
constexpr size_t kOffCbL = 65536 + 2097152;
constexpr size_t kOffWl  = 65536 + 2 * 2097152;
}

typedef short           bf16x8 __attribute__((ext_vector_type(8)));
typedef unsigned short  us16x8 __attribute__((ext_vector_type(8)));
typedef float           f32x4  __attribute__((ext_vector_type(4)));

__device__ __forceinline__ unsigned short f2bf_rne(float f) {
    unsigned int x = __float_as_uint(f);
    unsigned int r = (x + 0x7fffu + ((x >> 16) & 1u)) >> 16;
    return (unsigned short)r;
}
__device__ __forceinline__ float bf2f(unsigned short u) {
    return __uint_as_float(((unsigned int)u) << 16);
}

// ---------------------------------------------------------------------------
// Prep: split codebook into bf16 hi/lo and compute exact (fp64-accum) c_sq.
// One block per code (8192 blocks x 128 threads).
// ---------------------------------------------------------------------------
__global__ void pq_prep(const float* __restrict__ cb,
                        unsigned short* __restrict__ cbh,
                        unsigned short* __restrict__ cbl,
                        float* __restrict__ csq)
{
    int code = blockIdx.x;          // h*1024 + k
    int t = threadIdx.x;            // 0..127 (= d)
    float v = cb[(size_t)code * kD + t];
    unsigned short hb = f2bf_rne(v);
    unsigned short lb = f2bf_rne(v - bf2f(hb));
    cbh[(size_t)code * kD + t] = hb;
    cbl[(size_t)code * kD + t] = lb;
    __shared__ double red[128];
    red[t] = (double)v * (double)v;
    __syncthreads();
    for (int s = 64; s > 0; s >>= 1) {
        if (t < s) red[t] += red[t + s];
        __syncthreads();
    }
    if (t == 0) csq[code] = (float)red[0];
}

// ---------------------------------------------------------------------------
// Coarse MFMA pass. Block: 256 thr = 4 waves; one head, 64 z rows, 1024 codes.
// score[k] = c_sq[k] - 2*dot(z,c_k), dot via 3-way bf16-split MFMA (fp32 acc).
// Wave w owns rows [16w,16w+16); A-frags (z) live in regs for the whole block.
// LDS tiles XOR-swizzled: byte ^= (row&7)<<4  (conflict-free ds_read_b128).
// ---------------------------------------------------------------------------
__global__ __launch_bounds__(256, 2)
void pq_coarse_mfma(const float* __restrict__ z, const float* __restrict__ cb,
                    const unsigned short* __restrict__ cbh,
                    const unsigned short* __restrict__ cbl,
                    const float* __restrict__ csq,
                    float* __restrict__ out_zq, float* __restrict__ out_idx,
                    unsigned int* wl_count, unsigned int* wl, unsigned int wl_cap)
{
    __shared__ unsigned short zh[BM * kD];   // swizzled [row][d] bf16-hi
    __shared__ unsigned short zl[BM * kD];
    __shared__ unsigned short ch[64 * kD];   // swizzled [code][d] bf16-hi
    __shared__ unsigned short cl[64 * kD];
    __shared__ float csq_s[kK];
    __shared__ int   idx_s[BM];

    const int t    = threadIdx.x;
    const int h    = blockIdx.y;
    const int b0   = blockIdx.x * BM;
    const int lane = t & 63;
    const int w    = t >> 6;
    const int g    = lane >> 4;     // k-group 0..3
    const int lj   = lane & 15;     // row/col within 16

    // ---- stage z tile: fp32 -> bf16 hi/lo, swizzled ----
    {
        const int col  = t & 31;    // float4 column (d0 = col*4)
        const int row0 = t >> 5;    // 0..7
        #pragma unroll
        for (int it = 0; it < 8; ++it) {
            int r = row0 + 8 * it;
            float4 v = *(const float4*)(z + (size_t)(b0 + r) * (kNH * kD) + h * kD + col * 4);
            unsigned short h0 = f2bf_rne(v.x), h1 = f2bf_rne(v.y),
                           h2 = f2bf_rne(v.z), h3 = f2bf_rne(v.w);
            unsigned short l0 = f2bf_rne(v.x - bf2f(h0)), l1 = f2bf_rne(v.y - bf2f(h1)),
                           l2 = f2bf_rne(v.z - bf2f(h2)), l3 = f2bf_rne(v.w - bf2f(h3));
            int off = r * 256 + ((col * 8) ^ ((r & 7) << 4));
            ushort4 hv = {h0, h1, h2, h3}, lv = {l0, l1, l2, l3};
            *(ushort4*)((char*)zh + off) = hv;
            *(ushort4*)((char*)zl + off) = lv;
        }
        // csq for this head -> LDS
        float4 c4 = *(const float4*)(csq + h * kK + t * 4);
        *(float4*)&csq_s[t * 4] = c4;
    }
    __syncthreads();

    // ---- A fragments: rows 16w+lj, k-chunk kc, k-elems kc*32+g*8.. ----
    bf16x8 Ah[4], Al[4];
    {
        const int arow = 16 * w + lj;
        #pragma unroll
        for (int kc = 0; kc < 4; ++kc) {
            int off = arow * 256 + ((kc * 64 + g * 16) ^ ((arow & 7) << 4));
            Ah[kc] = *(const bf16x8*)((const char*)zh + off);
            Al[kc] = *(const bf16x8*)((const char*)zl + off);
        }
    }

    float best1[4], best2[4];
    int   ibest[4];
    #pragma unroll
    for (int i = 0; i < 4; ++i) { best1[i] = 3.4e38f; best2[i] = 3.4e38f; ibest[i] = 0; }

    for (int kt = 0; kt < kK / 64; ++kt) {
        __syncthreads();   // previous tile's readers done
        // ---- stage codebook tile (bf16 pre-split in ws), swizzled ----
        {
            const unsigned short* srcH = cbh + ((size_t)(h * kK + kt * 64)) * kD;
            const unsigned short* srcL = cbl + ((size_t)(h * kK + kt * 64)) * kD;
            #pragma unroll
            for (int i = 0; i < 4; ++i) {
                int cid = t + 256 * i;          // 0..1023 16B-chunks
                int code = cid >> 4, chk = cid & 15;
                int soff = code * kD + chk * 8; // ushort units
                int doff = code * 256 + ((chk * 16) ^ ((code & 7) << 4));
                *(us16x8*)((char*)ch + doff) = *(const us16x8*)(srcH + soff);
                *(us16x8*)((char*)cl + doff) = *(const us16x8*)(srcL + soff);
            }
        }
        __syncthreads();
        // ---- MFMA: acc[n] over 4 n-tiles, K=128 in 4 chunks x 3 splits ----
        f32x4 acc[4];
        #pragma unroll
        for (int n = 0; n < 4; ++n) acc[n] = (f32x4)0.0f;
        #pragma unroll
        for (int kc = 0; kc < 4; ++kc) {
            #pragma unroll
            for (int n = 0; n < 4; ++n) {
                int crow = n * 16 + lj;
                int off = crow * 256 + ((kc * 64 + g * 16) ^ ((crow & 7) << 4));
                bf16x8 Bh = *(const bf16x8*)((const char*)ch + off);
                bf16x8 Bl = *(const bf16x8*)((const char*)cl + off);
                acc[n] = __builtin_amdgcn_mfma_f32_16x16x32_bf16(Ah[kc], Bh, acc[n], 0, 0, 0);
                acc[n] = __builtin_amdgcn_mfma_f32_16x16x32_bf16(Ah[kc], Bl, acc[n], 0, 0, 0);
                acc[n] = __builtin_amdgcn_mfma_f32_16x16x32_bf16(Al[kc], Bh, acc[n], 0, 0, 0);
            }
        }
        // ---- scores + running top-2 (k ascending per lane) ----
        #pragma unroll
        for (int n = 0; n < 4; ++n) {
            int kg = kt * 64 + n * 16 + lj;
            float cs = csq_s[kg];
            #pragma unroll
            for (int i = 0; i < 4; ++i) {
                float s = fmaf(-2.0f, acc[n][i], cs);
                if (s < best1[i]) { best2[i] = best1[i]; best1[i] = s; ibest[i] = kg; }
                else if (s < best2[i]) { best2[i] = s; }
            }
        }
    }

    // ---- cross-lane top-2 reduce within each 16-lane group ----
    #pragma unroll
    for (int i = 0; i < 4; ++i) {
        float b1 = best1[i], b2 = best2[i];
        int i1 = ibest[i];
        #pragma unroll
        for (int m = 1; m < 16; m <<= 1) {
            float ob1 = __shfl_xor(b1, m);
            float ob2 = __shfl_xor(b2, m);
            int   oi1 = __shfl_xor(i1, m);
            if (ob1 < b1 || (ob1 == b1 && oi1 < i1)) {
                b2 = fminf(b1, ob2); b1 = ob1; i1 = oi1;
            } else {
                b2 = fminf(b2, ob1);
            }
        }
        if (lj == 0) {
            int r = 16 * w + 4 * g + i;          // local row (C layout: row=(lane>>4)*4+reg)
            idx_s[r] = i1;
            int gid = (b0 + r) * kNH + h;
            out_idx[gid] = (float)i1;
            if (wl_cap > 0u && (b2 - b1) <= kMarginMfma) {
                unsigned int pos = atomicAdd(wl_count, 1u);
                if (pos < wl_cap) wl[pos] = (unsigned int)gid;
            }
        }
    }
    __syncthreads();
    // ---- gather zq rows (exact fp32 codebook copies) ----
    {
        int r = t >> 2, q = t & 3;
        const float* src = cb + ((size_t)h * kK + idx_s[r]) * kD;
        float* dst = out_zq + (size_t)(b0 + r) * (kNH * kD) + h * kD;
        #pragma unroll
        for (int m = 0; m < 8; ++m) {
            int jj = 4 * m + q;
            *(float4*)(dst + 4 * jj) = *(const float4*)(src + 4 * jj);
        }
    }
}

// ---------------------------------------------------------------------------
// Fallback fp32 coarse pass (round-1, proven) — used only if ws too small.
// ---------------------------------------------------------------------------
__global__ __launch_bounds__(256, 2)
void pq_coarse_f32(const float* __restrict__ z, const float* __restrict__ cb,
                   float* __restrict__ out_zq, float* __restrict__ out_idx,
                   unsigned int* wl_count, unsigned int* wl, unsigned int wl_cap)
{
    constexpr int KT = 64, PAD = 68;
    __shared__ float zT[kD][PAD];
    __shared__ float cT[kD][PAD];
    __shared__ float csq_s[KT];
    __shared__ int   bidx_s[BM];

    const int t  = threadIdx.x;
    const int h  = blockIdx.y;
    const int b0 = blockIdx.x * BM;
    const int tx = t & 15, ty = t >> 4;
    const int r8 = t & 7,  d4 = t >> 3;

    {
        const float* zp = z + (size_t)(b0 + r8) * (kNH * kD) + h * kD + 4 * d4;
        #pragma unroll
        for (int it = 0; it < BM / 8; ++it) {
            float4 v = *(const float4*)(zp + (size_t)(8 * it) * (kNH * kD));
            int r = r8 + 8 * it;
            zT[4 * d4 + 0][r] = v.x; zT[4 * d4 + 1][r] = v.y;
            zT[4 * d4 + 2][r] = v.z; zT[4 * d4 + 3][r] = v.w;
        }
    }
    float best1[4], best2[4]; int ibest[4];
    #pragma unroll
    for (int i = 0; i < 4; ++i) { best1[i] = 3.4e38f; best2[i] = 3.4e38f; ibest[i] = 0; }

    for (int kt = 0; kt < kK / KT; ++kt) {
        __syncthreads();
        {
            const float* cp = cb + ((size_t)h * kK + kt * KT + r8) * kD + 4 * d4;
            #pragma unroll
            for (int it = 0; it < KT / 8; ++it) {
                float4 v = *(const float4*)(cp + (size_t)(8 * it) * kD);
                int r = r8 + 8 * it;
                cT[4 * d4 + 0][r] = v.x; cT[4 * d4 + 1][r] = v.y;
                cT[4 * d4 + 2][r] = v.z; cT[4 * d4 + 3][r] = v.w;
            }
        }
        if (t < KT) csq_s[t] = 0.0f;
        __syncthreads();
        {
            int kk = t & 63, part = t >> 6;
            float s = 0.f;
            #pragma unroll
            for (int i = 0; i < 32; ++i) { float v = cT[32 * part + i][kk]; s = fmaf(v, v, s); }
            atomicAdd(&csq_s[kk], s);
        }
        __syncthreads();
        float accA[4][4] = {{0}}, accB[4][4] = {{0}};
        #pragma unroll 2
        for (int d = 0; d < kD; d += 2) {
            float4 za = *(const float4*)&zT[d][4 * ty];
            float4 ca = *(const float4*)&cT[d][4 * tx];
            float4 zb = *(const float4*)&zT[d + 1][4 * ty];
            float4 cv = *(const float4*)&cT[d + 1][4 * tx];
            float zav[4] = {za.x, za.y, za.z, za.w}, cav[4] = {ca.x, ca.y, ca.z, ca.w};
            float zbv[4] = {zb.x, zb.y, zb.z, zb.w}, cbv[4] = {cv.x, cv.y, cv.z, cv.w};
            #pragma unroll
            for (int i = 0; i < 4; ++i)
                #pragma unroll
                for (int j = 0; j < 4; ++j) {
                    accA[i][j] = fmaf(zav[i], cav[j], accA[i][j]);
                    accB[i][j] = fmaf(zbv[i], cbv[j], accB[i][j]);
                }
        }
        #pragma unroll
        for (int j = 0; j < 4; ++j) {
            int kk = 4 * tx + j;
            float cs = csq_s[kk];
            int kg = kt * KT + kk;
            #pragma unroll
            for (int i = 0; i < 4; ++i) {
                float s = fmaf(-2.0f, accA[i][j] + accB[i][j], cs);
                if (s < best1[i]) { best2[i] = best1[i]; best1[i] = s; ibest[i] = kg; }
                else if (s < best2[i]) { best2[i] = s; }
            }
        }
    }
    __syncthreads();
    float* redv1 = &zT[0][0];
    float* redv2 = redv1 + BM * 16;
    int*   redi  = (int*)(redv2 + BM * 16);
    #pragma unroll
    for (int i = 0; i < 4; ++i) {
        int r = 4 * ty + i;
        redv1[r * 16 + tx] = best1[i]; redv2[r * 16 + tx] = best2[i]; redi[r * 16 + tx] = ibest[i];
    }
    __syncthreads();
    if (t < BM) {
        int r = t;
        float b1 = redv1[r * 16], b2 = redv2[r * 16];
        int i1 = redi[r * 16];
        #pragma unroll
        for (int x = 1; x < 16; ++x) {
            float vb1 = redv1[r * 16 + x], vb2 = redv2[r * 16 + x];
            int vi1 = redi[r * 16 + x];
            if (vb1 < b1 || (vb1 == b1 && vi1 < i1)) { b2 = fminf(b1, vb2); b1 = vb1; i1 = vi1; }
            else b2 = fminf(b2, vb1);
        }
        bidx_s[r] = i1;
        int gid = (b0 + r) * kNH + h;
        out_idx[gid] = (float)i1;
        if (wl_cap > 0u && (b2 - b1) <= kMarginF32) {
            unsigned int pos = atomicAdd(wl_count, 1u);
            if (pos < wl_cap) wl[pos] = (unsigned int)gid;
        }
    }
    __syncthreads();
    {
        int r = t >> 2, q = t & 3;
        const float* src = cb + ((size_t)h * kK + bidx_s[r]) * kD;
        float* dst = out_zq + (size_t)(b0 + r) * (kNH * kD) + h * kD;
        #pragma unroll
        for (int m = 0; m < 8; ++m) {
            int jj = 4 * m + q;
            *(float4*)(dst + 4 * jj) = *(const float4*)(src + 4 * jj);
        }
    }
}

// ---------------------------------------------------------------------------
// Exact fp64 rescore for flagged pairs.
// ---------------------------------------------------------------------------
__global__ __launch_bounds__(256)
void pq_exact(const float* __restrict__ z, const float* __restrict__ cb,
              float* __restrict__ out_zq, float* __restrict__ out_idx,
              const unsigned int* wl_count, const unsigned int* wl,
              unsigned int wl_cap)
{
    if (wl_cap == 0u) return;
    __shared__ float  zs[kD];
    __shared__ double rv[256];
    __shared__ int    ri[256];
    unsigned int n = *wl_count;
    if (n > wl_cap) n = wl_cap;
    const int t = threadIdx.x;
    for (unsigned int e = blockIdx.x; e < n; e += gridDim.x) {
        unsigned int id = wl[e];
        int b = (int)(id / kNH), h = (int)(id % kNH);
        if (t < kD) zs[t] = z[(size_t)b * (kNH * kD) + h * kD + t];
        __syncthreads();
        double bv = 1e300; int bi = 0;
        #pragma unroll
        for (int kk = 0; kk < 4; ++kk) {
            int k = t * 4 + kk;
            const float* c = cb + ((size_t)h * kK + k) * kD;
            double s = 0.0;
            for (int d = 0; d < kD; ++d) {
                double diff = (double)zs[d] - (double)c[d];
                s = fma(diff, diff, s);
            }
            if (s < bv) { bv = s; bi = k; }
        }
        rv[t] = bv; ri[t] = bi;
        __syncthreads();
        for (int s2 = 128; s2 > 0; s2 >>= 1) {
            if (t < s2) {
                if (rv[t + s2] < rv[t] || (rv[t + s2] == rv[t] && ri[t + s2] < ri[t])) {
                    rv[t] = rv[t + s2]; ri[t] = ri[t + s2];
                }
            }
            __syncthreads();
        }
        int kbest = ri[0];
        if (t == 0) out_idx[id] = (float)kbest;
        if (t < kD)
            out_zq[(size_t)b * (kNH * kD) + h * kD + t] =
                cb[((size_t)h * kK + kbest) * kD + t];
        __syncthreads();
    }
}

extern "C" void kernel_launch(void* const* d_in, const int* in_sizes, int n_in,
                              void* d_out, int out_size, void* d_ws, size_t ws_size,
                              hipStream_t stream)
{
    const float* z  = (const float*)d_in[0];
    const float* cb = (const float*)d_in[1];
    float* out_zq  = (float*)d_out;
    float* out_idx = out_zq + (size_t)kB * kNH * kD;
    char* ws = (char*)d_ws;

    if (ws_size >= kOffWl + 4096) {
        // ---- MFMA path ----
        unsigned int* wl_count = (unsigned int*)ws;
        unsigned int* wl = (unsigned int*)(ws + kOffWl);
        size_t c = (ws_size - kOffWl) / 4;
        unsigned int cap = (unsigned int)(c > 262144 ? 262144 : c);
        float* csq = (float*)(ws + kOffCsq);
        unsigned short* cbh = (unsigned short*)(ws + kOffCbH);
        unsigned short* cbl = (unsigned short*)(ws + kOffCbL);

        hipMemsetAsync(d_ws, 0, 4, stream);
        pq_prep<<<kNH * kK, kD, 0, stream>>>(cb, cbh, cbl, csq);
        dim3 grid(kB / BM, kNH);
        pq_coarse_mfma<<<grid, 256, 0, stream>>>(z, cb, cbh, cbl, csq,
                                                 out_zq, out_idx, wl_count, wl, cap);
        pq_exact<<<256, 256, 0, stream>>>(z, cb, out_zq, out_idx, wl_count, wl, cap);
    } else {
        // ---- fallback: proven round-1 fp32 path ----
        unsigned int* wl_count = (unsigned int*)ws;
        unsigned int* wl = wl_count + 1;
        unsigned int cap = 0;
        if (ws_size >= 64) {
            size_t c = ws_size / 4 - 1;
            cap = (unsigned int)(c > 262144 ? 262144 : c);
            hipMemsetAsync(d_ws, 0, 4, stream);
        }
        dim3 grid(kB / BM, kNH);
        pq_coarse_f32<<<grid, 256, 0, stream>>>(z, cb, out_zq, out_idx, wl_count, wl, cap);
        pq_exact<<<256, 256, 0, stream>>>(z, cb, out_zq, out_idx, wl_count, wl, cap);
    }
}

// Round 4
// 371.607 us; speedup vs baseline: 3.5247x; 1.1485x over previous
//
#include <hip/hip_runtime.h>

namespace {
constexpr int kNH = 8;
constexpr int kK  = 1024;
constexpr int kD  = 128;
constexpr int kB  = 32768;

constexpr int BM  = 128;        // z rows per block (MFMA path)
// Rescue margin in QUANTIZED-SCORE units (score*1024 bins). Flag iff
// (q2 - q1) <= kMarginQ. NOTE: comparing raw keys (q*1024+kg) was round-3's
// bug: same-bin pairs measured their INDEX distance, not score gap.
constexpr int kMarginQ = 4;
constexpr float kMarginF32 = 0.0625f;

// d_ws layout (MFMA path): [0]=wl_count u32; csq*1024 @4KB (32KB);
// cbh_sw @64KB (2MB, tile-major pre-swizzled); cbl_sw @64KB+2MB; wl @64KB+4MB.
constexpr size_t kOffCsq = 4096;
constexpr size_t kOffCbH = 65536;
constexpr size_t kOffCbL = 65536 + 2097152;
constexpr size_t kOffWl  = 65536 + 2 * 2097152;
}

typedef short bf16x8 __attribute__((ext_vector_type(8)));
typedef float f32x16 __attribute__((ext_vector_type(16)));

__device__ __forceinline__ unsigned short f2bf_rne(float f) {
    unsigned int x = __float_as_uint(f);
    unsigned int r = (x + 0x7fffu + ((x >> 16) & 1u)) >> 16;
    return (unsigned short)r;
}
__device__ __forceinline__ float bf2f(unsigned short u) {
    return __uint_as_float(((unsigned int)u) << 16);
}
__device__ __forceinline__ void load_lds16(const void* g, void* l) {
    __builtin_amdgcn_global_load_lds(
        (const __attribute__((address_space(1))) unsigned int*)g,
        (__attribute__((address_space(3))) unsigned int*)l, 16, 0, 0);
}

// ---------------------------------------------------------------------------
// Prep: split codebook to bf16 hi/lo written PRE-SWIZZLED in LDS-tile layout
// (64-code tiles, 256B rows, byte-chunk ^= (code&7)), plus exact csq*1024.
// ---------------------------------------------------------------------------
__global__ void pq_prep(const float* __restrict__ cb,
                        unsigned short* __restrict__ cbh,
                        unsigned short* __restrict__ cbl,
                        float* __restrict__ csq)
{
    int code = blockIdx.x;          // h*1024 + k
    int t = threadIdx.x;            // 0..127 (= d)
    int h = code >> 10, k = code & 1023;
    int kt = k >> 6, kl = k & 63;
    float v = cb[(size_t)code * kD + t];
    unsigned short hb = f2bf_rne(v);
    unsigned short lb = f2bf_rne(v - bf2f(hb));
    size_t base = ((size_t)(h * 16 + kt) * 64 + kl) * 256;          // bytes
    size_t off = base + (((t >> 3) << 4) ^ ((kl & 7) << 4)) + (t & 7) * 2;
    *(unsigned short*)((char*)cbh + off) = hb;
    *(unsigned short*)((char*)cbl + off) = lb;
    __shared__ double red[128];
    red[t] = (double)v * (double)v;
    __syncthreads();
    for (int s = 64; s > 0; s >>= 1) {
        if (t < s) red[t] += red[t + s];
        __syncthreads();
    }
    if (t == 0) csq[code] = (float)(red[0] * 1024.0);
}

// ---------------------------------------------------------------------------
// Coarse MFMA pass, 32x32x16. Block: 256 thr = 4 waves (2 row-grp x 2 col-grp),
// one head, 128 z rows, all 1024 codes. A (z, bf16 hi/lo split) fully in regs.
// B tiles (64 codes) double-buffered in LDS via global_load_lds from the
// pre-swizzled ws copy. Scores tracked as int keys: trunc(1024*score)*1024+k.
// ---------------------------------------------------------------------------
__global__ __launch_bounds__(256, 2)
void pq_coarse_mfma2(const float* __restrict__ z, const float* __restrict__ cb,
                     const unsigned short* __restrict__ cbh,
                     const unsigned short* __restrict__ cbl,
                     const float* __restrict__ csq1024,
                     float* __restrict__ out_zq, float* __restrict__ out_idx,
                     unsigned int* wl_count, unsigned int* wl, unsigned int wl_cap)
{
    __shared__ unsigned char cbuf[2][32768];   // [buf][ ch 16KB | cl 16KB ]
    __shared__ int red1[2 * BM], red2[2 * BM], idx_s[BM];

    const int t    = threadIdx.x;
    const int h    = blockIdx.y;
    const int b0   = blockIdx.x * BM;
    const int lane = t & 63;
    const int w    = t >> 6;
    const int rg   = w >> 1, cg = w & 1;
    const int l31  = lane & 31, h32 = lane >> 5;

    const char* tile0H = (const char*)cbh + (size_t)(h * 16) * 16384 + w * 1024 + lane * 16;
    const char* tile0L = (const char*)cbl + (size_t)(h * 16) * 16384 + w * 1024 + lane * 16;

#define STAGE(nb, kt_)                                                        \
    {                                                                         \
        _Pragma("unroll")                                                     \
        for (int j = 0; j < 4; ++j) {                                         \
            load_lds16(tile0H + (size_t)(kt_) * 16384 + j * 4096,             \
                       &cbuf[nb][j * 4096 + w * 1024]);                       \
            load_lds16(tile0L + (size_t)(kt_) * 16384 + j * 4096,             \
                       &cbuf[nb][16384 + j * 4096 + w * 1024]);               \
        }                                                                     \
    }

    STAGE(0, 0);   // tile 0 in flight while we build A-fragments

    // ---- A fragments: rows rg*64 + ti*32 + l31, k = kc*16 + h32*8 + j ----
    bf16x8 Ah[2][8], Al[2][8];
    {
        const float* zr = z + (size_t)(b0 + rg * 64 + l31) * (kNH * kD) + h * kD + h32 * 8;
        #pragma unroll
        for (int ti = 0; ti < 2; ++ti) {
            const float* zp = zr + (size_t)ti * 32 * (kNH * kD);
            #pragma unroll
            for (int kc = 0; kc < 8; ++kc) {
                float4 a = *(const float4*)(zp + kc * 16);
                float4 b = *(const float4*)(zp + kc * 16 + 4);
                float f[8] = {a.x, a.y, a.z, a.w, b.x, b.y, b.z, b.w};
                bf16x8 hv, lv;
                #pragma unroll
                for (int j = 0; j < 8; ++j) {
                    unsigned short hb = f2bf_rne(f[j]);
                    hv[j] = (short)hb;
                    lv[j] = (short)f2bf_rne(f[j] - bf2f(hb));
                }
                Ah[ti][kc] = hv;
                Al[ti][kc] = lv;
            }
        }
    }

    int b1[2][16], b2[2][16];
    #pragma unroll
    for (int ti = 0; ti < 2; ++ti)
        #pragma unroll
        for (int r = 0; r < 16; ++r) { b1[ti][r] = 0x7fffffff; b2[ti][r] = 0x7fffffff; }

    asm volatile("s_waitcnt vmcnt(0)" ::: "memory");
    __syncthreads();

    const int rowoff = (cg * 32 + l31) * 256;
    const int xmask  = (l31 & 7) << 4;

    int cur = 0;
    for (int kt = 0; kt < 16; ++kt) {
        if (kt < 15) STAGE(cur ^ 1, kt + 1);
        const float cs = csq1024[h * kK + kt * 64 + cg * 32 + l31];
        const int   kg = kt * 64 + cg * 32 + l31;

        f32x16 acc0 = (f32x16)0.0f, acc1 = (f32x16)0.0f;
        const unsigned char* bufp = &cbuf[cur][0];
        #pragma unroll
        for (int kc = 0; kc < 8; ++kc) {
            int col = (kc * 32 + h32 * 16) ^ xmask;
            bf16x8 Bh = *(const bf16x8*)(bufp + rowoff + col);
            bf16x8 Bl = *(const bf16x8*)(bufp + 16384 + rowoff + col);
            acc0 = __builtin_amdgcn_mfma_f32_32x32x16_bf16(Ah[0][kc], Bh, acc0, 0, 0, 0);
            acc0 = __builtin_amdgcn_mfma_f32_32x32x16_bf16(Al[0][kc], Bh, acc0, 0, 0, 0);
            acc0 = __builtin_amdgcn_mfma_f32_32x32x16_bf16(Ah[0][kc], Bl, acc0, 0, 0, 0);
            acc1 = __builtin_amdgcn_mfma_f32_32x32x16_bf16(Ah[1][kc], Bh, acc1, 0, 0, 0);
            acc1 = __builtin_amdgcn_mfma_f32_32x32x16_bf16(Al[1][kc], Bh, acc1, 0, 0, 0);
            acc1 = __builtin_amdgcn_mfma_f32_32x32x16_bf16(Ah[1][kc], Bl, acc1, 0, 0, 0);
        }
        // ---- branchless top-2 on int keys ----
        #pragma unroll
        for (int r = 0; r < 16; ++r) {
            {
                float kf = fmaf(acc0[r], -2048.0f, cs);
                int key = ((int)kf << 10) + kg;
                int mx = max(b1[0][r], key);
                b1[0][r] = min(b1[0][r], key);
                b2[0][r] = min(b2[0][r], mx);
            }
            {
                float kf = fmaf(acc1[r], -2048.0f, cs);
                int key = ((int)kf << 10) + kg;
                int mx = max(b1[1][r], key);
                b1[1][r] = min(b1[1][r], key);
                b2[1][r] = min(b2[1][r], mx);
            }
        }
        asm volatile("s_waitcnt vmcnt(0)" ::: "memory");
        __syncthreads();
        cur ^= 1;
    }
#undef STAGE

    // ---- cross-lane top-2 reduce (32 lanes share each row's columns) ----
    #pragma unroll
    for (int ti = 0; ti < 2; ++ti) {
        #pragma unroll
        for (int r = 0; r < 16; ++r) {
            int v1 = b1[ti][r], v2 = b2[ti][r];
            #pragma unroll
            for (int m = 1; m < 32; m <<= 1) {
                int o1 = __shfl_xor(v1, m);
                int o2 = __shfl_xor(v2, m);
                int mx = max(v1, o1);
                v1 = min(v1, o1);
                v2 = min(min(v2, o2), mx);
            }
            if (l31 == 0) {
                int row = rg * 64 + ti * 32 + (r & 3) + ((r >> 2) << 3) + h32 * 4;
                red1[row * 2 + cg] = v1;
                red2[row * 2 + cg] = v2;
            }
        }
    }
    __syncthreads();
    // ---- merge the two col-group halves, emit idx + worklist ----
    if (t < BM) {
        int a1 = red1[2 * t], c1 = red1[2 * t + 1];
        int a2 = red2[2 * t], c2 = red2[2 * t + 1];
        int v1 = min(a1, c1);
        int v2 = min(min(a2, c2), max(a1, c1));
        int idx = v1 & 1023;
        idx_s[t] = idx;
        int gid = (b0 + t) * kNH + h;
        out_idx[gid] = (float)idx;
        // Flag in quantized-score space (q = key>>10, arithmetic shift).
        // Unflagged => q-gap >= kMarginQ+1 => true gap > kMarginQ/1024 - 2*eps
        // => coarse argmin provably exact. Same-bin contenders => q-gap 0 =>
        // always flagged and rescued in fp64.
        if (wl_cap > 0u && ((v2 >> 10) - (v1 >> 10)) <= kMarginQ) {
            unsigned int pos = atomicAdd(wl_count, 1u);
            if (pos < wl_cap) wl[pos] = (unsigned int)gid;
        }
    }
    __syncthreads();
    // ---- gather zq rows (exact fp32 codebook copies) ----
    {
        int row = t >> 1, q = t & 1;
        const float* src = cb + ((size_t)h * kK + idx_s[row]) * kD + q * 64;
        float* dst = out_zq + (size_t)(b0 + row) * (kNH * kD) + h * kD + q * 64;
        #pragma unroll
        for (int m = 0; m < 16; ++m)
            ((float4*)dst)[m] = ((const float4*)src)[m];
    }
}

// ---------------------------------------------------------------------------
// Fallback fp32 coarse pass (round-1, proven) — used only if ws too small.
// ---------------------------------------------------------------------------
__global__ __launch_bounds__(256, 2)
void pq_coarse_f32(const float* __restrict__ z, const float* __restrict__ cb,
                   float* __restrict__ out_zq, float* __restrict__ out_idx,
                   unsigned int* wl_count, unsigned int* wl, unsigned int wl_cap)
{
    constexpr int KT = 64, PAD = 68, BMF = 64;
    __shared__ float zT[kD][PAD];
    __shared__ float cT[kD][PAD];
    __shared__ float csq_s[KT];
    __shared__ int   bidx_s[BMF];

    const int t  = threadIdx.x;
    const int h  = blockIdx.y;
    const int b0 = blockIdx.x * BMF;
    const int tx = t & 15, ty = t >> 4;
    const int r8 = t & 7,  d4 = t >> 3;

    {
        const float* zp = z + (size_t)(b0 + r8) * (kNH * kD) + h * kD + 4 * d4;
        #pragma unroll
        for (int it = 0; it < BMF / 8; ++it) {
            float4 v = *(const float4*)(zp + (size_t)(8 * it) * (kNH * kD));
            int r = r8 + 8 * it;
            zT[4 * d4 + 0][r] = v.x; zT[4 * d4 + 1][r] = v.y;
            zT[4 * d4 + 2][r] = v.z; zT[4 * d4 + 3][r] = v.w;
        }
    }
    float best1[4], best2[4]; int ibest[4];
    #pragma unroll
    for (int i = 0; i < 4; ++i) { best1[i] = 3.4e38f; best2[i] = 3.4e38f; ibest[i] = 0; }

    for (int kt = 0; kt < kK / KT; ++kt) {
        __syncthreads();
        {
            const float* cp = cb + ((size_t)h * kK + kt * KT + r8) * kD + 4 * d4;
            #pragma unroll
            for (int it = 0; it < KT / 8; ++it) {
                float4 v = *(const float4*)(cp + (size_t)(8 * it) * kD);
                int r = r8 + 8 * it;
                cT[4 * d4 + 0][r] = v.x; cT[4 * d4 + 1][r] = v.y;
                cT[4 * d4 + 2][r] = v.z; cT[4 * d4 + 3][r] = v.w;
            }
        }
        if (t < KT) csq_s[t] = 0.0f;
        __syncthreads();
        {
            int kk = t & 63, part = t >> 6;
            float s = 0.f;
            #pragma unroll
            for (int i = 0; i < 32; ++i) { float v = cT[32 * part + i][kk]; s = fmaf(v, v, s); }
            atomicAdd(&csq_s[kk], s);
        }
        __syncthreads();
        float accA[4][4] = {{0}}, accB[4][4] = {{0}};
        #pragma unroll 2
        for (int d = 0; d < kD; d += 2) {
            float4 za = *(const float4*)&zT[d][4 * ty];
            float4 ca = *(const float4*)&cT[d][4 * tx];
            float4 zb = *(const float4*)&zT[d + 1][4 * ty];
            float4 cv = *(const float4*)&cT[d + 1][4 * tx];
            float zav[4] = {za.x, za.y, za.z, za.w}, cav[4] = {ca.x, ca.y, ca.z, ca.w};
            float zbv[4] = {zb.x, zb.y, zb.z, zb.w}, cbv[4] = {cv.x, cv.y, cv.z, cv.w};
            #pragma unroll
            for (int i = 0; i < 4; ++i)
                #pragma unroll
                for (int j = 0; j < 4; ++j) {
                    accA[i][j] = fmaf(zav[i], cav[j], accA[i][j]);
                    accB[i][j] = fmaf(zbv[i], cbv[j], accB[i][j]);
                }
        }
        #pragma unroll
        for (int j = 0; j < 4; ++j) {
            int kk = 4 * tx + j;
            float cs = csq_s[kk];
            int kg = kt * KT + kk;
            #pragma unroll
            for (int i = 0; i < 4; ++i) {
                float s = fmaf(-2.0f, accA[i][j] + accB[i][j], cs);
                if (s < best1[i]) { best2[i] = best1[i]; best1[i] = s; ibest[i] = kg; }
                else if (s < best2[i]) { best2[i] = s; }
            }
        }
    }
    __syncthreads();
    float* redv1 = &zT[0][0];
    float* redv2 = redv1 + BMF * 16;
    int*   redi  = (int*)(redv2 + BMF * 16);
    #pragma unroll
    for (int i = 0; i < 4; ++i) {
        int r = 4 * ty + i;
        redv1[r * 16 + tx] = best1[i]; redv2[r * 16 + tx] = best2[i]; redi[r * 16 + tx] = ibest[i];
    }
    __syncthreads();
    if (t < BMF) {
        int r = t;
        float vb1_ = redv1[r * 16], vb2_ = redv2[r * 16];
        int i1 = redi[r * 16];
        #pragma unroll
        for (int x = 1; x < 16; ++x) {
            float nb1 = redv1[r * 16 + x], nb2 = redv2[r * 16 + x];
            int ni1 = redi[r * 16 + x];
            if (nb1 < vb1_ || (nb1 == vb1_ && ni1 < i1)) { vb2_ = fminf(vb1_, nb2); vb1_ = nb1; i1 = ni1; }
            else vb2_ = fminf(vb2_, nb1);
        }
        bidx_s[r] = i1;
        int gid = (b0 + r) * kNH + h;
        out_idx[gid] = (float)i1;
        if (wl_cap > 0u && (vb2_ - vb1_) <= kMarginF32) {
            unsigned int pos = atomicAdd(wl_count, 1u);
            if (pos < wl_cap) wl[pos] = (unsigned int)gid;
        }
    }
    __syncthreads();
    {
        int r = t >> 2, q = t & 3;
        const float* src = cb + ((size_t)h * kK + bidx_s[r]) * kD;
        float* dst = out_zq + (size_t)(b0 + r) * (kNH * kD) + h * kD;
        #pragma unroll
        for (int m = 0; m < 8; ++m) {
            int jj = 4 * m + q;
            *(float4*)(dst + 4 * jj) = *(const float4*)(src + 4 * jj);
        }
    }
}

// ---------------------------------------------------------------------------
// Exact fp64 rescore for flagged pairs.
// ---------------------------------------------------------------------------
__global__ __launch_bounds__(256)
void pq_exact(const float* __restrict__ z, const float* __restrict__ cb,
              float* __restrict__ out_zq, float* __restrict__ out_idx,
              const unsigned int* wl_count, const unsigned int* wl,
              unsigned int wl_cap)
{
    if (wl_cap == 0u) return;
    __shared__ float  zs[kD];
    __shared__ double rv[256];
    __shared__ int    ri[256];
    unsigned int n = *wl_count;
    if (n > wl_cap) n = wl_cap;
    const int t = threadIdx.x;
    for (unsigned int e = blockIdx.x; e < n; e += gridDim.x) {
        unsigned int id = wl[e];
        int b = (int)(id / kNH), h = (int)(id % kNH);
        if (t < kD) zs[t] = z[(size_t)b * (kNH * kD) + h * kD + t];
        __syncthreads();
        double bv = 1e300; int bi = 0;
        #pragma unroll
        for (int kk = 0; kk < 4; ++kk) {
            int k = t * 4 + kk;
            const float* c = cb + ((size_t)h * kK + k) * kD;
            double s = 0.0;
            for (int d = 0; d < kD; ++d) {
                double diff = (double)zs[d] - (double)c[d];
                s = fma(diff, diff, s);
            }
            if (s < bv) { bv = s; bi = k; }
        }
        rv[t] = bv; ri[t] = bi;
        __syncthreads();
        for (int s2 = 128; s2 > 0; s2 >>= 1) {
            if (t < s2) {
                if (rv[t + s2] < rv[t] || (rv[t + s2] == rv[t] && ri[t + s2] < ri[t])) {
                    rv[t] = rv[t + s2]; ri[t] = ri[t + s2];
                }
            }
            __syncthreads();
        }
        int kbest = ri[0];
        if (t == 0) out_idx[id] = (float)kbest;
        if (t < kD)
            out_zq[(size_t)b * (kNH * kD) + h * kD + t] =
                cb[((size_t)h * kK + kbest) * kD + t];
        __syncthreads();
    }
}

extern "C" void kernel_launch(void* const* d_in, const int* in_sizes, int n_in,
                              void* d_out, int out_size, void* d_ws, size_t ws_size,
                              hipStream_t stream)
{
    const float* z  = (const float*)d_in[0];
    const float* cb = (const float*)d_in[1];
    float* out_zq  = (float*)d_out;
    float* out_idx = out_zq + (size_t)kB * kNH * kD;
    char* ws = (char*)d_ws;

    if (ws_size >= kOffWl + 4096) {
        unsigned int* wl_count = (unsigned int*)ws;
        unsigned int* wl = (unsigned int*)(ws + kOffWl);
        size_t c = (ws_size - kOffWl) / 4;
        unsigned int cap = (unsigned int)(c > 262144 ? 262144 : c);
        float* csq = (float*)(ws + kOffCsq);
        unsigned short* cbh = (unsigned short*)(ws + kOffCbH);
        unsigned short* cbl = (unsigned short*)(ws + kOffCbL);

        hipMemsetAsync(d_ws, 0, 4, stream);
        pq_prep<<<kNH * kK, kD, 0, stream>>>(cb, cbh, cbl, csq);
        dim3 grid(kB / BM, kNH);
        pq_coarse_mfma2<<<grid, 256, 0, stream>>>(z, cb, cbh, cbl, csq,
                                                  out_zq, out_idx, wl_count, wl, cap);
        pq_exact<<<256, 256, 0, stream>>>(z, cb, out_zq, out_idx, wl_count, wl, cap);
    } else {
        unsigned int* wl_count = (unsigned int*)ws;
        unsigned int* wl = wl_count + 1;
        unsigned int cap = 0;
        if (ws_size >= 64) {
            size_t c = ws_size / 4 - 1;
            cap = (unsigned int)(c > 262144 ? 262144 : c);
            hipMemsetAsync(d_ws, 0, 4, stream);
        }
        dim3 grid(kB / 64, kNH);
        pq_coarse_f32<<<grid, 256, 0, stream>>>(z, cb, out_zq, out_idx, wl_count, wl, cap);
        pq_exact<<<256, 256, 0, stream>>>(z, cb, out_zq, out_idx, wl_count, wl, cap);
    }
}

// Round 5
// 252.905 us; speedup vs baseline: 5.1791x; 1.4694x over previous
//
#include <hip/hip_runtime.h>

namespace {
constexpr int kNH = 8;
constexpr int kK  = 1024;
constexpr int kD  = 128;
constexpr int kB  = 32768;

constexpr int BM  = 128;        // z rows per block (MFMA path)
// Rescue margin in QUANTIZED-SCORE units (score*1024 bins). Flag iff
// (q2 - q1) <= kMarginQ  (round-4-proven logic).
constexpr int kMarginQ = 4;
constexpr float kMarginF32 = 0.0625f;

// d_ws layout (MFMA path): [0]=wl_count u32; csq*1024 @4KB (32KB);
// cbf @64KB (4MB, fragment-ordered bf16 hi/lo); wl @64KB+8MB.
constexpr size_t kOffCsq = 4096;
constexpr size_t kOffCbF = 65536;
constexpr size_t kOffWl  = 65536 + 2 * 2097152;
}

typedef short bf16x8 __attribute__((ext_vector_type(8)));
typedef float f32x16 __attribute__((ext_vector_type(16)));

__device__ __forceinline__ unsigned short f2bf_rne(float f) {
    unsigned int x = __float_as_uint(f);
    unsigned int r = (x + 0x7fffu + ((x >> 16) & 1u)) >> 16;
    return (unsigned short)r;
}
__device__ __forceinline__ float bf2f(unsigned short u) {
    return __uint_as_float(((unsigned int)u) << 16);
}

// ---------------------------------------------------------------------------
// Prep: split codebook to bf16 hi/lo written FRAGMENT-ORDERED for direct
// global->VGPR MFMA B loads, plus exact csq*1024.
// Layout: per (h, kt(16), kc(8), cv(2)): 2048B = hi-chunk 1024B | lo-chunk
// 1024B; within a chunk, lane (l31,h32) holds 16B = codes cv*32+l31,
// k = kc*16 + h32*8 + j  (the HW-verified 32x32x16 B-fragment mapping).
// ---------------------------------------------------------------------------
__global__ void pq_prep(const float* __restrict__ cb,
                        unsigned short* __restrict__ cbf,
                        float* __restrict__ csq)
{
    int code = blockIdx.x;          // h*1024 + k
    int t = threadIdx.x;            // 0..127 (= d)
    int h = code >> 10, k = code & 1023;
    int kt = k >> 6, cv = (k >> 5) & 1, l31 = k & 31;
    int kc = t >> 4, hh = (t >> 3) & 1, j = t & 7;
    float v = cb[(size_t)code * kD + t];
    unsigned short hb = f2bf_rne(v);
    unsigned short lb = f2bf_rne(v - bf2f(hb));
    size_t base = ((((size_t)h * 16 + kt) * 8 + kc) * 2 + cv) * 2048;
    size_t off  = base + (hh * 32 + l31) * 16 + j * 2;
    *(unsigned short*)((char*)cbf + off)        = hb;
    *(unsigned short*)((char*)cbf + off + 1024) = lb;
    __shared__ double red[128];
    red[t] = (double)v * (double)v;
    __syncthreads();
    for (int s = 64; s > 0; s >>= 1) {
        if (t < s) red[t] += red[t + s];
        __syncthreads();
    }
    if (t == 0) csq[code] = (float)(red[0] * 1024.0);
}

// ---------------------------------------------------------------------------
// Coarse MFMA pass, 32x32x16, BARRIER-FREE main loop. Block: 256 thr =
// 4 waves; wave w owns rows w*32..w*32+31, all 1024 codes. A (z, bf16 hi/lo)
// in regs; B loaded global->VGPR from fragment-ordered ws copy through a
// 4-slot register pipeline (depth-2 prefetch); compiler inserts vmcnt.
// Scores as int keys trunc(1024*score)*1024+k, top-2 per row, q-bin margin.
// ---------------------------------------------------------------------------
__global__ __launch_bounds__(256, 2)
void pq_coarse_mfma3(const float* __restrict__ z, const float* __restrict__ cb,
                     const unsigned short* __restrict__ cbf,
                     const float* __restrict__ csq1024,
                     float* __restrict__ out_zq, float* __restrict__ out_idx,
                     unsigned int* wl_count, unsigned int* wl, unsigned int wl_cap)
{
    __shared__ float csq_s[kK];
    __shared__ int   idx_s[BM];

    const int t    = threadIdx.x;
    const int h    = blockIdx.y;
    const int b0   = blockIdx.x * BM;
    const int lane = t & 63;
    const int w    = t >> 6;
    const int l31  = lane & 31, h32 = lane >> 5;

    // ---- stage csq for this head into LDS (4KB) ----
    *(float4*)&csq_s[t * 4] = *(const float4*)(csq1024 + h * kK + t * 4);

    // ---- A fragments: row w*32 + l31, k = kc*16 + h32*8 + j ----
    bf16x8 Ah[8], Al[8];
    {
        const float* zr = z + (size_t)(b0 + w * 32 + l31) * (kNH * kD) + h * kD + h32 * 8;
        #pragma unroll
        for (int kc = 0; kc < 8; ++kc) {
            float4 a = *(const float4*)(zr + kc * 16);
            float4 b = *(const float4*)(zr + kc * 16 + 4);
            float f[8] = {a.x, a.y, a.z, a.w, b.x, b.y, b.z, b.w};
            bf16x8 hv, lv;
            #pragma unroll
            for (int j = 0; j < 8; ++j) {
                unsigned short hb = f2bf_rne(f[j]);
                hv[j] = (short)hb;
                lv[j] = (short)f2bf_rne(f[j] - bf2f(hb));
            }
            Ah[kc] = hv;
            Al[kc] = lv;
        }
    }
    __syncthreads();   // csq_s ready (only barrier before epilogue)

    int b1[16], b2[16];
    #pragma unroll
    for (int r = 0; r < 16; ++r) { b1[r] = 0x7fffffff; b2[r] = 0x7fffffff; }

    const char* bbase = (const char*)cbf + (size_t)h * 524288 + lane * 16;
#define LDSLOT(kt_, kc_, s_)                                                  \
    {                                                                         \
        const char* p_ = bbase + (size_t)(((kt_) * 8 + (kc_)) * 2) * 2048;    \
        Bh0[s_] = *(const bf16x8*)(p_);                                       \
        Bl0[s_] = *(const bf16x8*)(p_ + 1024);                                \
        Bh1[s_] = *(const bf16x8*)(p_ + 2048);                                \
        Bl1[s_] = *(const bf16x8*)(p_ + 3072);                                \
    }

    bf16x8 Bh0[4], Bl0[4], Bh1[4], Bl1[4];
    LDSLOT(0, 0, 0);
    LDSLOT(0, 1, 1);

    for (int kt = 0; kt < 16; ++kt) {
        f32x16 acc0 = (f32x16)0.0f, acc1 = (f32x16)0.0f;
        const int ktn = (kt + 1 < 16) ? kt + 1 : kt;   // tail clamp (reload, unused)
        #pragma unroll
        for (int kc = 0; kc < 8; ++kc) {
            const int s  = kc & 3;
            const int s2 = (kc + 2) & 3;
            if (kc < 6) {
                LDSLOT(kt, kc + 2, s2);
            } else {
                LDSLOT(ktn, kc - 6, s2);
            }
            __builtin_amdgcn_s_setprio(1);
            acc0 = __builtin_amdgcn_mfma_f32_32x32x16_bf16(Ah[kc], Bh0[s], acc0, 0, 0, 0);
            acc1 = __builtin_amdgcn_mfma_f32_32x32x16_bf16(Ah[kc], Bh1[s], acc1, 0, 0, 0);
            acc0 = __builtin_amdgcn_mfma_f32_32x32x16_bf16(Al[kc], Bh0[s], acc0, 0, 0, 0);
            acc1 = __builtin_amdgcn_mfma_f32_32x32x16_bf16(Al[kc], Bh1[s], acc1, 0, 0, 0);
            acc0 = __builtin_amdgcn_mfma_f32_32x32x16_bf16(Ah[kc], Bl0[s], acc0, 0, 0, 0);
            acc1 = __builtin_amdgcn_mfma_f32_32x32x16_bf16(Ah[kc], Bl1[s], acc1, 0, 0, 0);
            __builtin_amdgcn_s_setprio(0);
        }
        // ---- scores + branchless top-2 on int keys ----
        const float cs0 = csq_s[kt * 64 + l31];
        const float cs1 = csq_s[kt * 64 + 32 + l31];
        const int   kg0 = kt * 64 + l31, kg1 = kg0 + 32;
        #pragma unroll
        for (int r = 0; r < 16; ++r) {
            {
                float kf = fmaf(acc0[r], -2048.0f, cs0);
                int key = ((int)kf << 10) + kg0;
                int mx = max(b1[r], key);
                b1[r] = min(b1[r], key);
                b2[r] = min(b2[r], mx);
            }
            {
                float kf = fmaf(acc1[r], -2048.0f, cs1);
                int key = ((int)kf << 10) + kg1;
                int mx = max(b1[r], key);
                b1[r] = min(b1[r], key);
                b2[r] = min(b2[r], mx);
            }
        }
    }
#undef LDSLOT

    // ---- cross-lane top-2 reduce within each 32-lane (l31) group ----
    #pragma unroll
    for (int r = 0; r < 16; ++r) {
        int v1 = b1[r], v2 = b2[r];
        #pragma unroll
        for (int m = 1; m < 32; m <<= 1) {
            int o1 = __shfl_xor(v1, m);
            int o2 = __shfl_xor(v2, m);
            int mx = max(v1, o1);
            v1 = min(v1, o1);
            v2 = min(min(v2, o2), mx);
        }
        if (l31 == 0) {   // lanes 0 and 32 (h32 = 0,1)
            int row = w * 32 + (r & 3) + ((r >> 2) << 3) + h32 * 4;
            int idx = v1 & 1023;
            idx_s[row] = idx;
            int gid = (b0 + row) * kNH + h;
            out_idx[gid] = (float)idx;
            // q-bin margin (round-4-proven): unflagged => q-gap >= 5 =>
            // true gap > 3/1024 - 2*eps => coarse argmin provably exact.
            if (wl_cap > 0u && ((v2 >> 10) - (v1 >> 10)) <= kMarginQ) {
                unsigned int pos = atomicAdd(wl_count, 1u);
                if (pos < wl_cap) wl[pos] = (unsigned int)gid;
            }
        }
    }
    __syncthreads();
    // ---- gather zq rows: dense 512B slices (32 lanes per row-slice) ----
    {
        const float* cbh_row = cb + (size_t)h * kK * kD;
        #pragma unroll
        for (int it = 0; it < 16; ++it) {
            int c = it * 256 + t;          // 0..4095 float4-chunks
            int row = c >> 5, col4 = c & 31;
            *(float4*)(out_zq + (size_t)(b0 + row) * (kNH * kD) + h * kD + col4 * 4) =
                *(const float4*)(cbh_row + (size_t)idx_s[row] * kD + col4 * 4);
        }
    }
}

// ---------------------------------------------------------------------------
// Fallback fp32 coarse pass (round-1, proven) — used only if ws too small.
// ---------------------------------------------------------------------------
__global__ __launch_bounds__(256, 2)
void pq_coarse_f32(const float* __restrict__ z, const float* __restrict__ cb,
                   float* __restrict__ out_zq, float* __restrict__ out_idx,
                   unsigned int* wl_count, unsigned int* wl, unsigned int wl_cap)
{
    constexpr int KT = 64, PAD = 68, BMF = 64;
    __shared__ float zT[kD][PAD];
    __shared__ float cT[kD][PAD];
    __shared__ float csq_s[KT];
    __shared__ int   bidx_s[BMF];

    const int t  = threadIdx.x;
    const int h  = blockIdx.y;
    const int b0 = blockIdx.x * BMF;
    const int tx = t & 15, ty = t >> 4;
    const int r8 = t & 7,  d4 = t >> 3;

    {
        const float* zp = z + (size_t)(b0 + r8) * (kNH * kD) + h * kD + 4 * d4;
        #pragma unroll
        for (int it = 0; it < BMF / 8; ++it) {
            float4 v = *(const float4*)(zp + (size_t)(8 * it) * (kNH * kD));
            int r = r8 + 8 * it;
            zT[4 * d4 + 0][r] = v.x; zT[4 * d4 + 1][r] = v.y;
            zT[4 * d4 + 2][r] = v.z; zT[4 * d4 + 3][r] = v.w;
        }
    }
    float best1[4], best2[4]; int ibest[4];
    #pragma unroll
    for (int i = 0; i < 4; ++i) { best1[i] = 3.4e38f; best2[i] = 3.4e38f; ibest[i] = 0; }

    for (int kt = 0; kt < kK / KT; ++kt) {
        __syncthreads();
        {
            const float* cp = cb + ((size_t)h * kK + kt * KT + r8) * kD + 4 * d4;
            #pragma unroll
            for (int it = 0; it < KT / 8; ++it) {
                float4 v = *(const float4*)(cp + (size_t)(8 * it) * kD);
                int r = r8 + 8 * it;
                cT[4 * d4 + 0][r] = v.x; cT[4 * d4 + 1][r] = v.y;
                cT[4 * d4 + 2][r] = v.z; cT[4 * d4 + 3][r] = v.w;
            }
        }
        if (t < KT) csq_s[t] = 0.0f;
        __syncthreads();
        {
            int kk = t & 63, part = t >> 6;
            float s = 0.f;
            #pragma unroll
            for (int i = 0; i < 32; ++i) { float v = cT[32 * part + i][kk]; s = fmaf(v, v, s); }
            atomicAdd(&csq_s[kk], s);
        }
        __syncthreads();
        float accA[4][4] = {{0}}, accB[4][4] = {{0}};
        #pragma unroll 2
        for (int d = 0; d < kD; d += 2) {
            float4 za = *(const float4*)&zT[d][4 * ty];
            float4 ca = *(const float4*)&cT[d][4 * tx];
            float4 zb = *(const float4*)&zT[d + 1][4 * ty];
            float4 cv = *(const float4*)&cT[d + 1][4 * tx];
            float zav[4] = {za.x, za.y, za.z, za.w}, cav[4] = {ca.x, ca.y, ca.z, ca.w};
            float zbv[4] = {zb.x, zb.y, zb.z, zb.w}, cbv[4] = {cv.x, cv.y, cv.z, cv.w};
            #pragma unroll
            for (int i = 0; i < 4; ++i)
                #pragma unroll
                for (int j = 0; j < 4; ++j) {
                    accA[i][j] = fmaf(zav[i], cav[j], accA[i][j]);
                    accB[i][j] = fmaf(zbv[i], cbv[j], accB[i][j]);
                }
        }
        #pragma unroll
        for (int j = 0; j < 4; ++j) {
            int kk = 4 * tx + j;
            float cs = csq_s[kk];
            int kg = kt * KT + kk;
            #pragma unroll
            for (int i = 0; i < 4; ++i) {
                float s = fmaf(-2.0f, accA[i][j] + accB[i][j], cs);
                if (s < best1[i]) { best2[i] = best1[i]; best1[i] = s; ibest[i] = kg; }
                else if (s < best2[i]) { best2[i] = s; }
            }
        }
    }
    __syncthreads();
    float* redv1 = &zT[0][0];
    float* redv2 = redv1 + BMF * 16;
    int*   redi  = (int*)(redv2 + BMF * 16);
    #pragma unroll
    for (int i = 0; i < 4; ++i) {
        int r = 4 * ty + i;
        redv1[r * 16 + tx] = best1[i]; redv2[r * 16 + tx] = best2[i]; redi[r * 16 + tx] = ibest[i];
    }
    __syncthreads();
    if (t < BMF) {
        int r = t;
        float vb1_ = redv1[r * 16], vb2_ = redv2[r * 16];
        int i1 = redi[r * 16];
        #pragma unroll
        for (int x = 1; x < 16; ++x) {
            float nb1 = redv1[r * 16 + x], nb2 = redv2[r * 16 + x];
            int ni1 = redi[r * 16 + x];
            if (nb1 < vb1_ || (nb1 == vb1_ && ni1 < i1)) { vb2_ = fminf(vb1_, nb2); vb1_ = nb1; i1 = ni1; }
            else vb2_ = fminf(vb2_, nb1);
        }
        bidx_s[r] = i1;
        int gid = (b0 + r) * kNH + h;
        out_idx[gid] = (float)i1;
        if (wl_cap > 0u && (vb2_ - vb1_) <= kMarginF32) {
            unsigned int pos = atomicAdd(wl_count, 1u);
            if (pos < wl_cap) wl[pos] = (unsigned int)gid;
        }
    }
    __syncthreads();
    {
        int r = t >> 2, q = t & 3;
        const float* src = cb + ((size_t)h * kK + bidx_s[r]) * kD;
        float* dst = out_zq + (size_t)(b0 + r) * (kNH * kD) + h * kD;
        #pragma unroll
        for (int m = 0; m < 8; ++m) {
            int jj = 4 * m + q;
            *(float4*)(dst + 4 * jj) = *(const float4*)(src + 4 * jj);
        }
    }
}

// ---------------------------------------------------------------------------
// Exact fp64 rescore for flagged pairs.
// ---------------------------------------------------------------------------
__global__ __launch_bounds__(256)
void pq_exact(const float* __restrict__ z, const float* __restrict__ cb,
              float* __restrict__ out_zq, float* __restrict__ out_idx,
              const unsigned int* wl_count, const unsigned int* wl,
              unsigned int wl_cap)
{
    if (wl_cap == 0u) return;
    __shared__ float  zs[kD];
    __shared__ double rv[256];
    __shared__ int    ri[256];
    unsigned int n = *wl_count;
    if (n > wl_cap) n = wl_cap;
    const int t = threadIdx.x;
    for (unsigned int e = blockIdx.x; e < n; e += gridDim.x) {
        unsigned int id = wl[e];
        int b = (int)(id / kNH), h = (int)(id % kNH);
        if (t < kD) zs[t] = z[(size_t)b * (kNH * kD) + h * kD + t];
        __syncthreads();
        double bv = 1e300; int bi = 0;
        #pragma unroll
        for (int kk = 0; kk < 4; ++kk) {
            int k = t * 4 + kk;
            const float* c = cb + ((size_t)h * kK + k) * kD;
            double s = 0.0;
            for (int d = 0; d < kD; ++d) {
                double diff = (double)zs[d] - (double)c[d];
                s = fma(diff, diff, s);
            }
            if (s < bv) { bv = s; bi = k; }
        }
        rv[t] = bv; ri[t] = bi;
        __syncthreads();
        for (int s2 = 128; s2 > 0; s2 >>= 1) {
            if (t < s2) {
                if (rv[t + s2] < rv[t] || (rv[t + s2] == rv[t] && ri[t + s2] < ri[t])) {
                    rv[t] = rv[t + s2]; ri[t] = ri[t + s2];
                }
            }
            __syncthreads();
        }
        int kbest = ri[0];
        if (t == 0) out_idx[id] = (float)kbest;
        if (t < kD)
            out_zq[(size_t)b * (kNH * kD) + h * kD + t] =
                cb[((size_t)h * kK + kbest) * kD + t];
        __syncthreads();
    }
}

extern "C" void kernel_launch(void* const* d_in, const int* in_sizes, int n_in,
                              void* d_out, int out_size, void* d_ws, size_t ws_size,
                              hipStream_t stream)
{
    const float* z  = (const float*)d_in[0];
    const float* cb = (const float*)d_in[1];
    float* out_zq  = (float*)d_out;
    float* out_idx = out_zq + (size_t)kB * kNH * kD;
    char* ws = (char*)d_ws;

    if (ws_size >= kOffWl + 4096) {
        unsigned int* wl_count = (unsigned int*)ws;
        unsigned int* wl = (unsigned int*)(ws + kOffWl);
        size_t c = (ws_size - kOffWl) / 4;
        unsigned int cap = (unsigned int)(c > 262144 ? 262144 : c);
        float* csq = (float*)(ws + kOffCsq);
        unsigned short* cbf = (unsigned short*)(ws + kOffCbF);

        hipMemsetAsync(d_ws, 0, 4, stream);
        pq_prep<<<kNH * kK, kD, 0, stream>>>(cb, cbf, csq);
        dim3 grid(kB / BM, kNH);
        pq_coarse_mfma3<<<grid, 256, 0, stream>>>(z, cb, cbf, csq,
                                                  out_zq, out_idx, wl_count, wl, cap);
        pq_exact<<<256, 256, 0, stream>>>(z, cb, out_zq, out_idx, wl_count, wl, cap);
    } else {
        unsigned int* wl_count = (unsigned int*)ws;
        unsigned int* wl = wl_count + 1;
        unsigned int cap = 0;
        if (ws_size >= 64) {
            size_t c = ws_size / 4 - 1;
            cap = (unsigned int)(c > 262144 ? 262144 : c);
            hipMemsetAsync(d_ws, 0, 4, stream);
        }
        dim3 grid(kB / 64, kNH);
        pq_coarse_f32<<<grid, 256, 0, stream>>>(z, cb, out_zq, out_idx, wl_count, wl, cap);
        pq_exact<<<256, 256, 0, stream>>>(z, cb, out_zq, out_idx, wl_count, wl, cap);
    }
}

// Round 6
// 238.396 us; speedup vs baseline: 5.4943x; 1.0609x over previous
//
#include <hip/hip_runtime.h>

namespace {
constexpr int kNH = 8;
constexpr int kK  = 1024;
constexpr int kD  = 128;
constexpr int kB  = 32768;

constexpr int BM  = 128;        // rows per block (round-5 mid-tier path)
constexpr int kMarginQ = 4;     // q-bin rescue margin (proven round 4/5)
constexpr float kMarginF32 = 0.0625f;

// ws layout:
// [0] wl_count u32; csq*1024 @4KB (32KB); cbf @64KB (4MB fragment-ordered);
// partials @64KB+4MB (4MB, int2 per (row,half)); wl @64KB+8MB.
constexpr size_t kOffCsq  = 4096;
constexpr size_t kOffCbF  = 65536;
constexpr size_t kOffPart = 65536 + 4194304;
constexpr size_t kOffWl6  = 65536 + 8388608;          // new path worklist
constexpr size_t kOffWl5  = 65536 + 4194304;          // round-5 path worklist
}

typedef short           bf16x8 __attribute__((ext_vector_type(8)));
typedef unsigned short  us16x8 __attribute__((ext_vector_type(8)));
typedef float           f32x16 __attribute__((ext_vector_type(16)));

__device__ __forceinline__ unsigned short f2bf_rne(float f) {
    unsigned int x = __float_as_uint(f);
    unsigned int r = (x + 0x7fffu + ((x >> 16) & 1u)) >> 16;
    return (unsigned short)r;
}
__device__ __forceinline__ float bf2f(unsigned short u) {
    return __uint_as_float(((unsigned int)u) << 16);
}

// ---------------------------------------------------------------------------
// Prep: split codebook to bf16 hi/lo in fragment order + exact csq*1024.
// Per (h,kt,kc,cv) 2048B block: hi 1024B | lo 1024B; lane (h32*32+l31) holds
// 16B = code cv*32+l31, k = kc*16 + h32*8 + j.
// ---------------------------------------------------------------------------
__global__ void pq_prep(const float* __restrict__ cb,
                        unsigned short* __restrict__ cbf,
                        float* __restrict__ csq)
{
    int code = blockIdx.x;          // h*1024 + k
    int t = threadIdx.x;            // 0..127 (= d)
    int h = code >> 10, k = code & 1023;
    int kt = k >> 6, cv = (k >> 5) & 1, l31 = k & 31;
    int kc = t >> 4, hh = (t >> 3) & 1, j = t & 7;
    float v = cb[(size_t)code * kD + t];
    unsigned short hb = f2bf_rne(v);
    unsigned short lb = f2bf_rne(v - bf2f(hb));
    size_t base = ((((size_t)h * 16 + kt) * 8 + kc) * 2 + cv) * 2048;
    size_t off  = base + (hh * 32 + l31) * 16 + j * 2;
    *(unsigned short*)((char*)cbf + off)        = hb;
    *(unsigned short*)((char*)cbf + off + 1024) = lb;
    __shared__ double red[128];
    red[t] = (double)v * (double)v;
    __syncthreads();
    for (int s = 64; s > 0; s >>= 1) {
        if (t < s) red[t] += red[t + s];
        __syncthreads();
    }
    if (t == 0) csq[code] = (float)(red[0] * 1024.0);
}

// ---------------------------------------------------------------------------
// Coarse pass v4: code-resident waves. Block = 512 thr = 8 waves; one head,
// one 512-code half, 1024 z rows. Wave w holds its 64-code hi/lo panel in
// regs as MFMA *A*; z rows stream via LDS (hi/lo split, XOR-swizzle, dbuf,
// T14 issue/commit split) as MFMA *B*. C col = lane = z-row => per-lane
// top-2 needs 2 regs, no shuffles. Per-tile cross-wave merge -> ws partials.
// ---------------------------------------------------------------------------
__global__ __launch_bounds__(512, 2)
void pq_coarse_mfma4(const float* __restrict__ z,
                     const unsigned short* __restrict__ cbf,
                     const float* __restrict__ csq1024,
                     int2* __restrict__ part)
{
    __shared__ unsigned short zbuf[2][2][32 * kD];   // [dbuf][hi/lo][row*128+d] swz
    __shared__ int2 P[2][8][32];                     // per-tile wave partials

    const int t    = threadIdx.x;
    const int lane = t & 63;
    const int w    = t >> 6;          // wave 0..7
    const int l31  = lane & 31, h32 = lane >> 5;
    const int h    = blockIdx.y;
    const int half = blockIdx.z;
    const int rb0  = blockIdx.x * 1024;

    // ---- A panel: wave's 64 codes (kt = half*8 + w), hi/lo, 128 VGPR ----
    bf16x8 Ah[8][2], Al[8][2];
    {
        const char* base = (const char*)cbf
            + (((size_t)h * 16 + half * 8 + w) * 16) * 2048 + lane * 16;
        #pragma unroll
        for (int kc = 0; kc < 8; ++kc)
            #pragma unroll
            for (int cv = 0; cv < 2; ++cv) {
                const char* p = base + (size_t)(kc * 2 + cv) * 2048;
                Ah[kc][cv] = *(const bf16x8*)p;
                Al[kc][cv] = *(const bf16x8*)(p + 1024);
            }
    }
    // ---- csel: csq*1024 for this lane's acc elements ----
    float csel[2][16];
    {
        const float* cs = csq1024 + h * kK + half * 512 + w * 64 + h32 * 4;
        #pragma unroll
        for (int cv = 0; cv < 2; ++cv)
            #pragma unroll
            for (int r = 0; r < 16; ++r)
                csel[cv][r] = cs[cv * 32 + (r & 3) + ((r >> 2) << 3)];
    }

    float4 zA, zB;   // pending z loads (T14 issue-early / commit-late)
    auto issueZ = [&](int tile) {
        const float* zp = z + (size_t)(rb0 + tile * 32 + (t >> 4)) * (kNH * kD)
                            + h * kD + (t & 15) * 8;
        zA = *(const float4*)zp;
        zB = *(const float4*)(zp + 4);
    };
    auto commitZ = [&](int buf) {
        float f[8] = {zA.x, zA.y, zA.z, zA.w, zB.x, zB.y, zB.z, zB.w};
        us16x8 hv, lv;
        #pragma unroll
        for (int j = 0; j < 8; ++j) {
            unsigned short hb = f2bf_rne(f[j]);
            hv[j] = hb;
            lv[j] = f2bf_rne(f[j] - bf2f(hb));
        }
        int r = t >> 4, seg = t & 15;
        int off = r * 256 + ((seg * 16) ^ ((r & 15) << 4));
        *(us16x8*)((char*)&zbuf[buf][0][0] + off) = hv;
        *(us16x8*)((char*)&zbuf[buf][1][0] + off) = lv;
    };
    auto mergeP = [&](int pb, int tile) {   // threads 0..31 only
        int2 m = P[pb][0][t];
        int m1 = m.x, m2 = m.y;
        #pragma unroll
        for (int ww = 1; ww < 8; ++ww) {
            int2 p = P[pb][ww][t];
            int mx = max(m1, p.x);
            m1 = min(m1, p.x);
            m2 = min(min(m2, p.y), mx);
        }
        int gid = (rb0 + tile * 32 + t) * kNH + h;
        part[(size_t)gid * 2 + half] = make_int2(m1, m2);
    };

    issueZ(0);
    commitZ(0);
    __syncthreads();

    int cur = 0;
    const int cgb = half * 512 + w * 64 + h32 * 4;
    for (int tile = 0; tile < 32; ++tile) {
        if (tile + 1 < 32) issueZ(tile + 1);
        if (tile > 0 && t < 32) mergeP(cur ^ 1, tile - 1);

        f32x16 acc0 = (f32x16)0.0f, acc1 = (f32x16)0.0f;
        const char* zh0 = (const char*)&zbuf[cur][0][0];
        const char* zl0 = (const char*)&zbuf[cur][1][0];
        const int boff = l31 * 256;
        const int swz  = (l31 & 15) << 4;
        #pragma unroll
        for (int kc = 0; kc < 8; ++kc) {
            int col = (kc * 32 + h32 * 16) ^ swz;
            bf16x8 Bh = *(const bf16x8*)(zh0 + boff + col);
            bf16x8 Bl = *(const bf16x8*)(zl0 + boff + col);
            __builtin_amdgcn_s_setprio(1);
            acc0 = __builtin_amdgcn_mfma_f32_32x32x16_bf16(Ah[kc][0], Bh, acc0, 0, 0, 0);
            acc1 = __builtin_amdgcn_mfma_f32_32x32x16_bf16(Ah[kc][1], Bh, acc1, 0, 0, 0);
            acc0 = __builtin_amdgcn_mfma_f32_32x32x16_bf16(Al[kc][0], Bh, acc0, 0, 0, 0);
            acc1 = __builtin_amdgcn_mfma_f32_32x32x16_bf16(Al[kc][1], Bh, acc1, 0, 0, 0);
            acc0 = __builtin_amdgcn_mfma_f32_32x32x16_bf16(Ah[kc][0], Bl, acc0, 0, 0, 0);
            acc1 = __builtin_amdgcn_mfma_f32_32x32x16_bf16(Ah[kc][1], Bl, acc1, 0, 0, 0);
            __builtin_amdgcn_s_setprio(0);
        }
        // ---- per-lane (per z-row) branchless top-2 over 32 codes ----
        int b1 = 0x7fffffff, b2 = 0x7fffffff;
        #pragma unroll
        for (int r = 0; r < 16; ++r) {
            int cr = (r & 3) + ((r >> 2) << 3);
            {
                float kf = fmaf(acc0[r], -2048.0f, csel[0][r]);
                int key = ((int)kf << 10) + cgb + cr;
                int mx = max(b1, key); b1 = min(b1, key); b2 = min(b2, mx);
            }
            {
                float kf = fmaf(acc1[r], -2048.0f, csel[1][r]);
                int key = ((int)kf << 10) + cgb + cr + 32;
                int mx = max(b1, key); b1 = min(b1, key); b2 = min(b2, mx);
            }
        }
        // fold the two half-wave code sets (same z-row lives in lane l and l+32)
        int o1 = __shfl_xor(b1, 32), o2 = __shfl_xor(b2, 32);
        int mx2 = max(b1, o1);
        int v1 = min(b1, o1);
        int v2 = min(min(b2, o2), mx2);
        if (h32 == 0) P[cur][w][l31] = make_int2(v1, v2);

        if (tile + 1 < 32) commitZ(cur ^ 1);
        __syncthreads();
        cur ^= 1;
    }
    if (t < 32) mergeP(cur ^ 1, 31);
}

// ---------------------------------------------------------------------------
// Merge the two code-half partials per row: idx, worklist flag, zq gather.
// ---------------------------------------------------------------------------
__global__ __launch_bounds__(256)
void pq_merge(const int2* __restrict__ part, const float* __restrict__ cb,
              float* __restrict__ out_zq, float* __restrict__ out_idx,
              unsigned int* wl_count, unsigned int* wl, unsigned int wl_cap)
{
    __shared__ int idx_s[128];
    const int t = threadIdx.x;
    const int g0 = blockIdx.x * 128;
    if (t < 128) {
        int gid = g0 + t;
        int2 p0 = part[(size_t)gid * 2];
        int2 p1 = part[(size_t)gid * 2 + 1];
        int mx = max(p0.x, p1.x);
        int v1 = min(p0.x, p1.x);
        int v2 = min(min(p0.y, p1.y), mx);
        int idx = v1 & 1023;
        idx_s[t] = idx;
        out_idx[gid] = (float)idx;
        if (wl_cap > 0u && ((v2 >> 10) - (v1 >> 10)) <= kMarginQ) {
            unsigned int pos = atomicAdd(wl_count, 1u);
            if (pos < wl_cap) wl[pos] = (unsigned int)gid;
        }
    }
    __syncthreads();
    #pragma unroll
    for (int it = 0; it < 16; ++it) {
        int c = it * 256 + t;          // 0..4095 float4 chunks
        int row = c >> 5, c4 = c & 31;
        int gid = g0 + row;
        int b = gid >> 3, hh = gid & 7;
        *(float4*)(out_zq + (size_t)b * (kNH * kD) + hh * kD + c4 * 4) =
            *(const float4*)(cb + ((size_t)hh * kK + idx_s[row]) * kD + c4 * 4);
    }
}

// ---------------------------------------------------------------------------
// Round-5 coarse kernel (proven, 253us) — mid-tier fallback.
// ---------------------------------------------------------------------------
__global__ __launch_bounds__(256, 2)
void pq_coarse_mfma3(const float* __restrict__ z, const float* __restrict__ cb,
                     const unsigned short* __restrict__ cbf,
                     const float* __restrict__ csq1024,
                     float* __restrict__ out_zq, float* __restrict__ out_idx,
                     unsigned int* wl_count, unsigned int* wl, unsigned int wl_cap)
{
    __shared__ float csq_s[kK];
    __shared__ int   idx_s[BM];

    const int t    = threadIdx.x;
    const int h    = blockIdx.y;
    const int b0   = blockIdx.x * BM;
    const int lane = t & 63;
    const int w    = t >> 6;
    const int l31  = lane & 31, h32 = lane >> 5;

    *(float4*)&csq_s[t * 4] = *(const float4*)(csq1024 + h * kK + t * 4);

    bf16x8 Ah[8], Al[8];
    {
        const float* zr = z + (size_t)(b0 + w * 32 + l31) * (kNH * kD) + h * kD + h32 * 8;
        #pragma unroll
        for (int kc = 0; kc < 8; ++kc) {
            float4 a = *(const float4*)(zr + kc * 16);
            float4 b = *(const float4*)(zr + kc * 16 + 4);
            float f[8] = {a.x, a.y, a.z, a.w, b.x, b.y, b.z, b.w};
            bf16x8 hv, lv;
            #pragma unroll
            for (int j = 0; j < 8; ++j) {
                unsigned short hb = f2bf_rne(f[j]);
                hv[j] = (short)hb;
                lv[j] = (short)f2bf_rne(f[j] - bf2f(hb));
            }
            Ah[kc] = hv;
            Al[kc] = lv;
        }
    }
    __syncthreads();

    int b1[16], b2[16];
    #pragma unroll
    for (int r = 0; r < 16; ++r) { b1[r] = 0x7fffffff; b2[r] = 0x7fffffff; }

    const char* bbase = (const char*)cbf + (size_t)h * 524288 + lane * 16;
#define LDSLOT(kt_, kc_, s_)                                                  \
    {                                                                         \
        const char* p_ = bbase + (size_t)(((kt_) * 8 + (kc_)) * 2) * 2048;    \
        Bh0[s_] = *(const bf16x8*)(p_);                                       \
        Bl0[s_] = *(const bf16x8*)(p_ + 1024);                                \
        Bh1[s_] = *(const bf16x8*)(p_ + 2048);                                \
        Bl1[s_] = *(const bf16x8*)(p_ + 3072);                                \
    }

    bf16x8 Bh0[4], Bl0[4], Bh1[4], Bl1[4];
    LDSLOT(0, 0, 0);
    LDSLOT(0, 1, 1);

    for (int kt = 0; kt < 16; ++kt) {
        f32x16 acc0 = (f32x16)0.0f, acc1 = (f32x16)0.0f;
        const int ktn = (kt + 1 < 16) ? kt + 1 : kt;
        #pragma unroll
        for (int kc = 0; kc < 8; ++kc) {
            const int s  = kc & 3;
            const int s2 = (kc + 2) & 3;
            if (kc < 6) { LDSLOT(kt, kc + 2, s2); } else { LDSLOT(ktn, kc - 6, s2); }
            __builtin_amdgcn_s_setprio(1);
            acc0 = __builtin_amdgcn_mfma_f32_32x32x16_bf16(Ah[kc], Bh0[s], acc0, 0, 0, 0);
            acc1 = __builtin_amdgcn_mfma_f32_32x32x16_bf16(Ah[kc], Bh1[s], acc1, 0, 0, 0);
            acc0 = __builtin_amdgcn_mfma_f32_32x32x16_bf16(Al[kc], Bh0[s], acc0, 0, 0, 0);
            acc1 = __builtin_amdgcn_mfma_f32_32x32x16_bf16(Al[kc], Bh1[s], acc1, 0, 0, 0);
            acc0 = __builtin_amdgcn_mfma_f32_32x32x16_bf16(Ah[kc], Bl0[s], acc0, 0, 0, 0);
            acc1 = __builtin_amdgcn_mfma_f32_32x32x16_bf16(Ah[kc], Bl1[s], acc1, 0, 0, 0);
            __builtin_amdgcn_s_setprio(0);
        }
        const float cs0 = csq_s[kt * 64 + l31];
        const float cs1 = csq_s[kt * 64 + 32 + l31];
        const int   kg0 = kt * 64 + l31, kg1 = kg0 + 32;
        #pragma unroll
        for (int r = 0; r < 16; ++r) {
            {
                float kf = fmaf(acc0[r], -2048.0f, cs0);
                int key = ((int)kf << 10) + kg0;
                int mx = max(b1[r], key); b1[r] = min(b1[r], key); b2[r] = min(b2[r], mx);
            }
            {
                float kf = fmaf(acc1[r], -2048.0f, cs1);
                int key = ((int)kf << 10) + kg1;
                int mx = max(b1[r], key); b1[r] = min(b1[r], key); b2[r] = min(b2[r], mx);
            }
        }
    }
#undef LDSLOT

    #pragma unroll
    for (int r = 0; r < 16; ++r) {
        int v1 = b1[r], v2 = b2[r];
        #pragma unroll
        for (int m = 1; m < 32; m <<= 1) {
            int o1 = __shfl_xor(v1, m);
            int o2 = __shfl_xor(v2, m);
            int mx = max(v1, o1);
            v1 = min(v1, o1);
            v2 = min(min(v2, o2), mx);
        }
        if (l31 == 0) {
            int row = w * 32 + (r & 3) + ((r >> 2) << 3) + h32 * 4;
            int idx = v1 & 1023;
            idx_s[row] = idx;
            int gid = (b0 + row) * kNH + h;
            out_idx[gid] = (float)idx;
            if (wl_cap > 0u && ((v2 >> 10) - (v1 >> 10)) <= kMarginQ) {
                unsigned int pos = atomicAdd(wl_count, 1u);
                if (pos < wl_cap) wl[pos] = (unsigned int)gid;
            }
        }
    }
    __syncthreads();
    {
        const float* cbh_row = cb + (size_t)h * kK * kD;
        #pragma unroll
        for (int it = 0; it < 16; ++it) {
            int c = it * 256 + t;
            int row = c >> 5, col4 = c & 31;
            *(float4*)(out_zq + (size_t)(b0 + row) * (kNH * kD) + h * kD + col4 * 4) =
                *(const float4*)(cbh_row + (size_t)idx_s[row] * kD + col4 * 4);
        }
    }
}

// ---------------------------------------------------------------------------
// Fallback fp32 coarse pass (round-1, proven) — used only if ws tiny.
// ---------------------------------------------------------------------------
__global__ __launch_bounds__(256, 2)
void pq_coarse_f32(const float* __restrict__ z, const float* __restrict__ cb,
                   float* __restrict__ out_zq, float* __restrict__ out_idx,
                   unsigned int* wl_count, unsigned int* wl, unsigned int wl_cap)
{
    constexpr int KT = 64, PAD = 68, BMF = 64;
    __shared__ float zT[kD][PAD];
    __shared__ float cT[kD][PAD];
    __shared__ float csq_s[KT];
    __shared__ int   bidx_s[BMF];

    const int t  = threadIdx.x;
    const int h  = blockIdx.y;
    const int b0 = blockIdx.x * BMF;
    const int tx = t & 15, ty = t >> 4;
    const int r8 = t & 7,  d4 = t >> 3;

    {
        const float* zp = z + (size_t)(b0 + r8) * (kNH * kD) + h * kD + 4 * d4;
        #pragma unroll
        for (int it = 0; it < BMF / 8; ++it) {
            float4 v = *(const float4*)(zp + (size_t)(8 * it) * (kNH * kD));
            int r = r8 + 8 * it;
            zT[4 * d4 + 0][r] = v.x; zT[4 * d4 + 1][r] = v.y;
            zT[4 * d4 + 2][r] = v.z; zT[4 * d4 + 3][r] = v.w;
        }
    }
    float best1[4], best2[4]; int ibest[4];
    #pragma unroll
    for (int i = 0; i < 4; ++i) { best1[i] = 3.4e38f; best2[i] = 3.4e38f; ibest[i] = 0; }

    for (int kt = 0; kt < kK / KT; ++kt) {
        __syncthreads();
        {
            const float* cp = cb + ((size_t)h * kK + kt * KT + r8) * kD + 4 * d4;
            #pragma unroll
            for (int it = 0; it < KT / 8; ++it) {
                float4 v = *(const float4*)(cp + (size_t)(8 * it) * kD);
                int r = r8 + 8 * it;
                cT[4 * d4 + 0][r] = v.x; cT[4 * d4 + 1][r] = v.y;
                cT[4 * d4 + 2][r] = v.z; cT[4 * d4 + 3][r] = v.w;
            }
        }
        if (t < KT) csq_s[t] = 0.0f;
        __syncthreads();
        {
            int kk = t & 63, part = t >> 6;
            float s = 0.f;
            #pragma unroll
            for (int i = 0; i < 32; ++i) { float v = cT[32 * part + i][kk]; s = fmaf(v, v, s); }
            atomicAdd(&csq_s[kk], s);
        }
        __syncthreads();
        float accA[4][4] = {{0}}, accB[4][4] = {{0}};
        #pragma unroll 2
        for (int d = 0; d < kD; d += 2) {
            float4 za = *(const float4*)&zT[d][4 * ty];
            float4 ca = *(const float4*)&cT[d][4 * tx];
            float4 zb = *(const float4*)&zT[d + 1][4 * ty];
            float4 cv = *(const float4*)&cT[d + 1][4 * tx];
            float zav[4] = {za.x, za.y, za.z, za.w}, cav[4] = {ca.x, ca.y, ca.z, ca.w};
            float zbv[4] = {zb.x, zb.y, zb.z, zb.w}, cbv[4] = {cv.x, cv.y, cv.z, cv.w};
            #pragma unroll
            for (int i = 0; i < 4; ++i)
                #pragma unroll
                for (int j = 0; j < 4; ++j) {
                    accA[i][j] = fmaf(zav[i], cav[j], accA[i][j]);
                    accB[i][j] = fmaf(zbv[i], cbv[j], accB[i][j]);
                }
        }
        #pragma unroll
        for (int j = 0; j < 4; ++j) {
            int kk = 4 * tx + j;
            float cs = csq_s[kk];
            int kg = kt * KT + kk;
            #pragma unroll
            for (int i = 0; i < 4; ++i) {
                float s = fmaf(-2.0f, accA[i][j] + accB[i][j], cs);
                if (s < best1[i]) { best2[i] = best1[i]; best1[i] = s; ibest[i] = kg; }
                else if (s < best2[i]) { best2[i] = s; }
            }
        }
    }
    __syncthreads();
    float* redv1 = &zT[0][0];
    float* redv2 = redv1 + BMF * 16;
    int*   redi  = (int*)(redv2 + BMF * 16);
    #pragma unroll
    for (int i = 0; i < 4; ++i) {
        int r = 4 * ty + i;
        redv1[r * 16 + tx] = best1[i]; redv2[r * 16 + tx] = best2[i]; redi[r * 16 + tx] = ibest[i];
    }
    __syncthreads();
    if (t < BMF) {
        int r = t;
        float vb1_ = redv1[r * 16], vb2_ = redv2[r * 16];
        int i1 = redi[r * 16];
        #pragma unroll
        for (int x = 1; x < 16; ++x) {
            float nb1 = redv1[r * 16 + x], nb2 = redv2[r * 16 + x];
            int ni1 = redi[r * 16 + x];
            if (nb1 < vb1_ || (nb1 == vb1_ && ni1 < i1)) { vb2_ = fminf(vb1_, nb2); vb1_ = nb1; i1 = ni1; }
            else vb2_ = fminf(vb2_, nb1);
        }
        bidx_s[r] = i1;
        int gid = (b0 + r) * kNH + h;
        out_idx[gid] = (float)i1;
        if (wl_cap > 0u && (vb2_ - vb1_) <= kMarginF32) {
            unsigned int pos = atomicAdd(wl_count, 1u);
            if (pos < wl_cap) wl[pos] = (unsigned int)gid;
        }
    }
    __syncthreads();
    {
        int r = t >> 2, q = t & 3;
        const float* src = cb + ((size_t)h * kK + bidx_s[r]) * kD;
        float* dst = out_zq + (size_t)(b0 + r) * (kNH * kD) + h * kD;
        #pragma unroll
        for (int m = 0; m < 8; ++m) {
            int jj = 4 * m + q;
            *(float4*)(dst + 4 * jj) = *(const float4*)(src + 4 * jj);
        }
    }
}

// ---------------------------------------------------------------------------
// Exact fp64 rescore for flagged pairs.
// ---------------------------------------------------------------------------
__global__ __launch_bounds__(256)
void pq_exact(const float* __restrict__ z, const float* __restrict__ cb,
              float* __restrict__ out_zq, float* __restrict__ out_idx,
              const unsigned int* wl_count, const unsigned int* wl,
              unsigned int wl_cap)
{
    if (wl_cap == 0u) return;
    __shared__ float  zs[kD];
    __shared__ double rv[256];
    __shared__ int    ri[256];
    unsigned int n = *wl_count;
    if (n > wl_cap) n = wl_cap;
    const int t = threadIdx.x;
    for (unsigned int e = blockIdx.x; e < n; e += gridDim.x) {
        unsigned int id = wl[e];
        int b = (int)(id / kNH), h = (int)(id % kNH);
        if (t < kD) zs[t] = z[(size_t)b * (kNH * kD) + h * kD + t];
        __syncthreads();
        double bv = 1e300; int bi = 0;
        #pragma unroll
        for (int kk = 0; kk < 4; ++kk) {
            int k = t * 4 + kk;
            const float* c = cb + ((size_t)h * kK + k) * kD;
            double s = 0.0;
            for (int d = 0; d < kD; ++d) {
                double diff = (double)zs[d] - (double)c[d];
                s = fma(diff, diff, s);
            }
            if (s < bv) { bv = s; bi = k; }
        }
        rv[t] = bv; ri[t] = bi;
        __syncthreads();
        for (int s2 = 128; s2 > 0; s2 >>= 1) {
            if (t < s2) {
                if (rv[t + s2] < rv[t] || (rv[t + s2] == rv[t] && ri[t + s2] < ri[t])) {
                    rv[t] = rv[t + s2]; ri[t] = ri[t + s2];
                }
            }
            __syncthreads();
        }
        int kbest = ri[0];
        if (t == 0) out_idx[id] = (float)kbest;
        if (t < kD)
            out_zq[(size_t)b * (kNH * kD) + h * kD + t] =
                cb[((size_t)h * kK + kbest) * kD + t];
        __syncthreads();
    }
}

extern "C" void kernel_launch(void* const* d_in, const int* in_sizes, int n_in,
                              void* d_out, int out_size, void* d_ws, size_t ws_size,
                              hipStream_t stream)
{
    const float* z  = (const float*)d_in[0];
    const float* cb = (const float*)d_in[1];
    float* out_zq  = (float*)d_out;
    float* out_idx = out_zq + (size_t)kB * kNH * kD;
    char* ws = (char*)d_ws;

    if (ws_size >= kOffWl6 + 65536) {
        // ---- new path: code-resident waves + merge ----
        unsigned int* wl_count = (unsigned int*)ws;
        unsigned int* wl = (unsigned int*)(ws + kOffWl6);
        size_t c = (ws_size - kOffWl6) / 4;
        unsigned int cap = (unsigned int)(c > 262144 ? 262144 : c);
        float* csq = (float*)(ws + kOffCsq);
        unsigned short* cbf = (unsigned short*)(ws + kOffCbF);
        int2* part = (int2*)(ws + kOffPart);

        hipMemsetAsync(d_ws, 0, 4, stream);
        pq_prep<<<kNH * kK, kD, 0, stream>>>(cb, cbf, csq);
        dim3 grid(32, kNH, 2);
        pq_coarse_mfma4<<<grid, 512, 0, stream>>>(z, cbf, csq, part);
        pq_merge<<<kB * kNH / 128, 256, 0, stream>>>(part, cb, out_zq, out_idx,
                                                     wl_count, wl, cap);
        pq_exact<<<256, 256, 0, stream>>>(z, cb, out_zq, out_idx, wl_count, wl, cap);
    } else if (ws_size >= kOffWl5 + 4096) {
        // ---- round-5 proven path ----
        unsigned int* wl_count = (unsigned int*)ws;
        unsigned int* wl = (unsigned int*)(ws + kOffWl5);
        size_t c = (ws_size - kOffWl5) / 4;
        unsigned int cap = (unsigned int)(c > 262144 ? 262144 : c);
        float* csq = (float*)(ws + kOffCsq);
        unsigned short* cbf = (unsigned short*)(ws + kOffCbF);

        hipMemsetAsync(d_ws, 0, 4, stream);
        pq_prep<<<kNH * kK, kD, 0, stream>>>(cb, cbf, csq);
        dim3 grid(kB / BM, kNH);
        pq_coarse_mfma3<<<grid, 256, 0, stream>>>(z, cb, cbf, csq,
                                                  out_zq, out_idx, wl_count, wl, cap);
        pq_exact<<<256, 256, 0, stream>>>(z, cb, out_zq, out_idx, wl_count, wl, cap);
    } else {
        unsigned int* wl_count = (unsigned int*)ws;
        unsigned int* wl = wl_count + 1;
        unsigned int cap = 0;
        if (ws_size >= 64) {
            size_t c = ws_size / 4 - 1;
            cap = (unsigned int)(c > 262144 ? 262144 : c);
            hipMemsetAsync(d_ws, 0, 4, stream);
        }
        dim3 grid(kB / 64, kNH);
        pq_coarse_f32<<<grid, 256, 0, stream>>>(z, cb, out_zq, out_idx, wl_count, wl, cap);
        pq_exact<<<256, 256, 0, stream>>>(z, cb, out_zq, out_idx, wl_count, wl, cap);
    }
}